// Round 11
// baseline (228.278 us; speedup 1.0000x reference)
//
#include <hip/hip_runtime.h>
#include <math.h>

typedef __bf16 bf16;
typedef __bf16 bf16x8 __attribute__((ext_vector_type(8)));
typedef __bf16 bf16x4 __attribute__((ext_vector_type(4)));
typedef float  f32x4  __attribute__((ext_vector_type(4)));

namespace {
constexpr int B_ = 2, S_ = 2048, HID_ = 1024, H_ = 16, D_ = 64, R_ = 128, NREL_ = 257;
constexpr float LOG2E_ = 1.44269504f;
constexpr float QSC_ = 0.125f * LOG2E_;   // 1/sqrt(D) and log2(e), folded into Q
}

static __device__ __forceinline__ f32x4 mfma16(bf16x8 a, bf16x8 b, f32x4 c) {
  return __builtin_amdgcn_mfma_f32_16x16x32_bf16(a, b, c, 0, 0, 0);
}
static __device__ __forceinline__ void split2(float f, bf16 &hi, bf16 &lo) {
  hi = (bf16)f; lo = (bf16)(f - (float)hi);
}
// async global->LDS, 16B per lane. dst must be wave-uniform base (+lane*16 by HW).
static __device__ __forceinline__ void gload16(const bf16* g, bf16* l) {
  __builtin_amdgcn_global_load_lds(
      (const __attribute__((address_space(1))) void*)g,
      (__attribute__((address_space(3))) void*)l, 16, 0, 0);
}

// ---------------- prep: mask, rkE*8, rvE^T, hidden split (Ah/Al), W -> bf16
__global__ __launch_bounds__(256) void prep_kernel(
    const float* __restrict__ st_mask, const float* __restrict__ rkE,
    const float* __restrict__ rvE, const float* __restrict__ hidden,
    const float* __restrict__ Wq, const float* __restrict__ Wk,
    const float* __restrict__ Wv,
    float* __restrict__ msk2, bf16* __restrict__ rkEb, bf16* __restrict__ rvTb,
    bf16* __restrict__ Ahg, bf16* __restrict__ Alg, bf16* __restrict__ Wbg)
{
  const int t0 = blockIdx.x * 256 + threadIdx.x;
  const int NT = gridDim.x * 256;
  for (int t = t0; t < B_ * S_; t += NT)
    msk2[t] = (1.f - st_mask[t]) * -10000.f * LOG2E_;
  for (int t = t0; t < 272 * 64; t += NT) {
    const int bk = t >> 6, d = t & 63;
    rkEb[t] = (bk < NREL_) ? (bf16)(rkE[bk * D_ + d] * 8.0f) : (bf16)0.f;
  }
  for (int t = t0; t < 64 * 288; t += NT) {
    const int d = t / 288, c = t - d * 288;
    rvTb[t] = (c < NREL_) ? (bf16)rvE[c * D_ + d] : (bf16)0.f;
  }
  // hidden split: 4096*1024 f32 -> Ah/Al bf16
  for (int t = t0; t < (B_ * S_ * HID_) / 4; t += NT) {
    const float4 a = ((const float4*)hidden)[t];
    const float av[4] = {a.x, a.y, a.z, a.w};
    bf16x4 h, o;
#pragma unroll
    for (int i = 0; i < 4; ++i) {
      bf16 th, tl;
      split2(av[i], th, tl);
      h[i] = th; o[i] = tl;
    }
    *(bf16x4*)&Ahg[t * 4] = h;
    *(bf16x4*)&Alg[t * 4] = o;
  }
  // W -> bf16 (single), [3][1024][1024]
  for (int t = t0; t < 3 * (HID_ * HID_) / 4; t += NT) {
    const int s = t >> 18, i = t & 262143;
    const float4 wv4 = ((const float4*)(s == 0 ? Wq : s == 1 ? Wk : Wv))[i];
    bf16x4 h;
    h[0] = (bf16)wv4.x; h[1] = (bf16)wv4.y; h[2] = (bf16)wv4.z; h[3] = (bf16)wv4.w;
    *(bf16x4*)&Wbg[s * 1048576 + i * 4] = h;
  }
}

// ---------------- qkv GEMM (passed r10): pure bf16, gload_lds dbuf 2-phase.
// V now written TILED [B,H, S/64, D, 64] for full-tile swizzled PV staging.
__global__ __launch_bounds__(256, 2) void qkv_mfma_kernel(
    const bf16* __restrict__ Ahg, const bf16* __restrict__ Alg,
    const bf16* __restrict__ Wbg,
    const float* __restrict__ bq, const float* __restrict__ bk,
    const float* __restrict__ bv,
    bf16* __restrict__ Qh, bf16* __restrict__ Ql,
    bf16* __restrict__ Kb, bf16* __restrict__ Vt)
{
  const int swz = ((int)blockIdx.x & 7) * 64 + ((int)blockIdx.x >> 3);
  const int m0 = (swz >> 4) * 128;
  const int n0 = (swz & 15) * 64;
  const int tid = threadIdx.x;
  const int l = tid & 63, w = tid >> 6;
  const int cl = l & 15, g = l >> 4;

  __shared__ __align__(16) bf16 AhS[2][4096];
  __shared__ __align__(16) bf16 AlS[2][4096];
  __shared__ __align__(16) bf16 WS[2][3][2048];

  const int r0 = tid >> 2;
  const int csw = (((tid & 3) ^ (r0 & 3)) << 3);
  const size_t aoff0 = (size_t)(m0 + r0) * HID_ + csw;
  const size_t aoff1 = (size_t)(m0 + 64 + r0) * HID_ + csw;
  const size_t woff  = (size_t)(n0 + r0) * HID_ + csw;
  const int wb = w * 512;

  const int rA0 = w * 16 + cl;
  const int eA0 = rA0 * 32 + 8 * (g ^ (rA0 & 3));
  const int eA1 = eA0 + 2048;
  const int eW  = cl * 32 + 8 * (g ^ (cl & 3));

  f32x4 acc[2][3][4];
#pragma unroll
  for (int hf = 0; hf < 2; ++hf)
#pragma unroll
    for (int s = 0; s < 3; ++s)
#pragma unroll
      for (int nf = 0; nf < 4; ++nf)
#pragma unroll
        for (int i = 0; i < 4; ++i) acc[hf][s][nf][i] = 0.f;

  gload16(Ahg + aoff0, &AhS[0][wb]);
  gload16(Ahg + aoff1, &AhS[0][2048 + wb]);
  gload16(Alg + aoff0, &AlS[0][wb]);
  gload16(Alg + aoff1, &AlS[0][2048 + wb]);
  gload16(Wbg + woff,           &WS[0][0][wb]);
  gload16(Wbg + 1048576 + woff, &WS[0][1][wb]);
  gload16(Wbg + 2097152 + woff, &WS[0][2][wb]);
  __syncthreads();

  int cur = 0;
  for (int kt = 0; kt < HID_ / 32; ++kt) {
    if (kt + 1 < HID_ / 32) {
      const size_t ko = (size_t)(kt + 1) * 32;
      bf16* ah = &AhS[cur ^ 1][0]; bf16* al = &AlS[cur ^ 1][0];
      gload16(Ahg + aoff0 + ko, ah + wb);
      gload16(Ahg + aoff1 + ko, ah + 2048 + wb);
      gload16(Alg + aoff0 + ko, al + wb);
      gload16(Alg + aoff1 + ko, al + 2048 + wb);
      gload16(Wbg + woff + ko,           &WS[cur ^ 1][0][wb]);
      gload16(Wbg + 1048576 + woff + ko, &WS[cur ^ 1][1][wb]);
      gload16(Wbg + 2097152 + woff + ko, &WS[cur ^ 1][2][wb]);
    }

    const bf16x8 fah0 = *(const bf16x8*)&AhS[cur][eA0];
    const bf16x8 fah1 = *(const bf16x8*)&AhS[cur][eA1];
    const bf16x8 fal0 = *(const bf16x8*)&AlS[cur][eA0];
    const bf16x8 fal1 = *(const bf16x8*)&AlS[cur][eA1];
#pragma unroll
    for (int s = 0; s < 3; ++s)
#pragma unroll
      for (int nf = 0; nf < 4; ++nf) {
        const bf16x8 fb = *(const bf16x8*)&WS[cur][s][nf * 512 + eW];
        acc[0][s][nf] = mfma16(fah0, fb, acc[0][s][nf]);
        acc[0][s][nf] = mfma16(fal0, fb, acc[0][s][nf]);
        acc[1][s][nf] = mfma16(fah1, fb, acc[1][s][nf]);
        acc[1][s][nf] = mfma16(fal1, fb, acc[1][s][nf]);
      }
    __syncthreads();
    cur ^= 1;
  }

  const float* bs_[3] = {bq, bk, bv};
#pragma unroll
  for (int s = 0; s < 3; ++s)
#pragma unroll
    for (int nf = 0; nf < 4; ++nf) {
      const int n = n0 + nf * 16 + cl;
      const float bias = bs_[s][n];
      const int hd = n >> 6, d = n & 63;
#pragma unroll
      for (int hf = 0; hf < 2; ++hf)
#pragma unroll
        for (int reg = 0; reg < 4; ++reg) {
          const int m = m0 + hf * 64 + w * 16 + g * 4 + reg;
          const int b = m >> 11, sq = m & (S_ - 1);
          const float val = acc[hf][s][nf][reg] + bias;
          if (s == 0) {
            bf16 h, o; split2(val * QSC_, h, o);
            const size_t idx = ((size_t)(b * H_ + hd) * S_ + sq) * D_ + d;
            Qh[idx] = h; Ql[idx] = o;
          } else if (s == 1) {
            Kb[((size_t)(b * H_ + hd) * S_ + sq) * D_ + d] = (bf16)val;
          } else {
            // tiled: [B,H, S/64, D, 64]
            Vt[(((size_t)(b * H_ + hd) * (S_ / 64) + (sq >> 6)) * D_ + d) * 64 + (sq & 63)]
                = (bf16)val;
          }
        }
    }
}

// ---------------- attention v11: T table in GLOBAL scratch (LDS 43.8KB -> 3 wg/CU),
// V full-tile [64d][64j] 8-chunk XOR swizzle, setprio on MFMA clusters.
__global__ __launch_bounds__(512, 6) void attn_kernel(
    const bf16* __restrict__ Qh, const bf16* __restrict__ Ql,
    const bf16* __restrict__ Kb, const bf16* __restrict__ Vt,
    const float* __restrict__ msk2, const bf16* __restrict__ rkEb,
    const bf16* __restrict__ rvTb, bf16* __restrict__ Tg,
    float* __restrict__ out)
{
  const int swz = ((int)blockIdx.x & 7) * 128 + ((int)blockIdx.x >> 3);
  const int qt = swz & 31, h = (swz >> 5) & 15, b = swz >> 9;
  const int q0 = qt * 64;
  const int tid = threadIdx.x;
  const int l = tid & 63, w = tid >> 6;
  const int wq = (w & 3) * 16;
  const int wh = w >> 2;
  const int cl = l & 15, g = l >> 4, kg8 = g * 8;
  const int lq = wq + cl;

  __shared__ __align__(16) bf16 k_s[2][4096];   // [64 j][64 d], 8-chunk swz
  __shared__ __align__(16) bf16 v_s[2][4096];   // [64 d][64 j], 8-chunk swz
  __shared__ __align__(16) bf16 ph[64][72];
  __shared__ float red[2][3][64];
  __shared__ float lsum_s[64];

  bf16* Tw = Tg + (size_t)swz * (64 * 288);     // this wg's rs/relp table
  bf16* Tq = Tw + (size_t)lq * 288;             // this lane's row

  const size_t bh = (size_t)(b * H_ + h) * S_;
  const bf16* Kbase = Kb + bh * D_;             // [S][64]
  const bf16* Vbase = Vt + bh * D_;             // tiled [S/64][64][64]
  const float* mbase = msk2 + b * S_;

  // staging source offsets (inverse-swizzled; dest linear)
  const int tKr = tid >> 3;
  const int koff = tKr * 64 + (((tid & 7) ^ (tKr & 7)) << 3);
  const int voff = koff;                        // same [64][64] 8-chunk pattern
  bf16* kdst0 = &k_s[0][w * 512]; bf16* kdst1 = &k_s[1][w * 512];
  bf16* vdst0 = &v_s[0][w * 512]; bf16* vdst1 = &v_s[1][w * 512];

  gload16(Kbase + koff, kdst0);
  gload16(Vbase + voff, vdst0);

  bf16x8 qh0, qh1, ql0, ql1;
  {
    const size_t base = (bh + q0 + lq) * D_ + kg8;
    qh0 = *(const bf16x8*)(Qh + base);
    qh1 = *(const bf16x8*)(Qh + base + 32);
    ql0 = *(const bf16x8*)(Ql + base);
    ql1 = *(const bf16x8*)(Ql + base + 32);
  }

  // rel key scores into Tw (global)
  {
    const int nt0 = wh ? 9 : 0, ntE = wh ? 17 : 9;
    for (int nt = nt0; nt < ntE; ++nt) {
      f32x4 r; r[0] = r[1] = r[2] = r[3] = 0.f;
      const bf16x8 a0 = *(const bf16x8*)(rkEb + (size_t)(nt * 16 + cl) * 64 + kg8);
      const bf16x8 a1 = *(const bf16x8*)(rkEb + (size_t)(nt * 16 + cl) * 64 + 32 + kg8);
      r = mfma16(a0, qh0, r); r = mfma16(a0, ql0, r);
      r = mfma16(a1, qh1, r); r = mfma16(a1, ql1, r);
      bf16x4 pk;
#pragma unroll
      for (int reg = 0; reg < 4; ++reg) pk[reg] = (bf16)r[reg];
      *(bf16x4*)&Tq[nt * 16 + g * 4] = pk;
    }
  }
  __syncthreads();   // Tw visible (same-CU L1); kt=0 stage drained

  const float rs_lo = (float)Tq[0];
  const float rs_hi = (float)Tq[2 * R_];
  const int qg = q0 + lq;

  f32x4 ctx0, ctx1;
#pragma unroll
  for (int i = 0; i < 4; ++i) { ctx0[i] = 0.f; ctx1[i] = 0.f; }
  float lsum = 0.f, plo = 0.f, phi = 0.f;

  const int r00 = wh * 32 + cl, r10 = wh * 32 + 16 + cl;
  const int e00 = r00 * 64 + 8 * (g ^ (r00 & 7)), e01 = r00 * 64 + 8 * ((4 + g) ^ (r00 & 7));
  const int e10 = r10 * 64 + 8 * (g ^ (r10 & 7)), e11 = r10 * 64 + 8 * ((4 + g) ^ (r10 & 7));
  const int f0  = r00 * 64 + 8 * (g ^ (r00 & 7)), f0b = r00 * 64 + 8 * ((4 + g) ^ (r00 & 7));
  const int f1  = r10 * 64 + 8 * (g ^ (r10 & 7)), f1b = r10 * 64 + 8 * ((4 + g) ^ (r10 & 7));

  int cur = 0;
  for (int kt = 0; kt < S_ / 64; ++kt) {
    if (kt + 1 < S_ / 64) {
      gload16(Kbase + (size_t)(kt + 1) * 4096 + koff, cur ? kdst0 : kdst1);
      gload16(Vbase + (size_t)(kt + 1) * 4096 + voff, cur ? vdst0 : vdst1);
    }

    const bf16* kc = &k_s[cur][0];
    const bf16x8 a00 = *(const bf16x8*)&kc[e00];
    const bf16x8 a01 = *(const bf16x8*)&kc[e01];
    const bf16x8 a10 = *(const bf16x8*)&kc[e10];
    const bf16x8 a11 = *(const bf16x8*)&kc[e11];

    f32x4 s0, s1;
    s0[0]=s0[1]=s0[2]=s0[3]=0.f; s1[0]=s1[1]=s1[2]=s1[3]=0.f;
    __builtin_amdgcn_s_setprio(1);
    s0 = mfma16(a00, qh0, s0); s0 = mfma16(a00, ql0, s0);
    s0 = mfma16(a01, qh1, s0); s0 = mfma16(a01, ql1, s0);
    s1 = mfma16(a10, qh0, s1); s1 = mfma16(a10, ql0, s1);
    s1 = mfma16(a11, qh1, s1); s1 = mfma16(a11, ql1, s1);
    __builtin_amdgcn_s_setprio(0);

    const int j0 = kt * 64 + wh * 32;
    const float4 mk0 = *(const float4*)(mbase + j0 + g * 4);
    const float4 mk1 = *(const float4*)(mbase + j0 + 16 + g * 4);
    const int dlt = kt * 64 - q0;
    const int mode = (dlt <= -192) ? 0 : (dlt >= 192 ? 1 : 2);

#pragma unroll
    for (int nf = 0; nf < 2; ++nf) {
      const f32x4 sa = nf ? s1 : s0;
      const float4 mkv = nf ? mk1 : mk0;
      const float mks[4] = {mkv.x, mkv.y, mkv.z, mkv.w};
      float p[4];
      if (mode == 0) {
#pragma unroll
        for (int reg = 0; reg < 4; ++reg) p[reg] = exp2f(sa[reg] + rs_lo + mks[reg]);
        plo += (p[0] + p[1]) + (p[2] + p[3]);
      } else if (mode == 1) {
#pragma unroll
        for (int reg = 0; reg < 4; ++reg) p[reg] = exp2f(sa[reg] + rs_hi + mks[reg]);
        phi += (p[0] + p[1]) + (p[2] + p[3]);
      } else {
        const int jb = j0 + nf * 16 + g * 4;
#pragma unroll
        for (int reg = 0; reg < 4; ++reg) {
          const int bkv = jb + reg - qg + R_;
          const int bkc = bkv < 0 ? 0 : (bkv > 2 * R_ ? 2 * R_ : bkv);
          const float pv = exp2f(sa[reg] + (float)Tq[bkc] + mks[reg]);
          p[reg] = pv;
          if (bkv <= 0)           plo += pv;
          else if (bkv >= 2 * R_) phi += pv;
          else                    Tq[bkv] = (bf16)pv;   // unique owner cell
        }
      }
      lsum += (p[0] + p[1]) + (p[2] + p[3]);
      bf16x4 pk;
#pragma unroll
      for (int reg = 0; reg < 4; ++reg) pk[reg] = (bf16)p[reg];
      *(bf16x4*)&ph[lq][wh * 32 + nf * 16 + g * 4] = pk;
    }
    __syncthreads();   // barrier1: P written, next stage drained

    const bf16x8 pa0 = *(const bf16x8*)&ph[lq][kg8];
    const bf16x8 pa1 = *(const bf16x8*)&ph[lq][32 + kg8];
    const bf16* vc = &v_s[cur][0];
    const bf16x8 vb00 = *(const bf16x8*)&vc[f0];
    const bf16x8 vb01 = *(const bf16x8*)&vc[f0b];
    const bf16x8 vb10 = *(const bf16x8*)&vc[f1];
    const bf16x8 vb11 = *(const bf16x8*)&vc[f1b];
    __builtin_amdgcn_s_setprio(1);
    ctx0 = mfma16(pa0, vb00, ctx0); ctx0 = mfma16(pa1, vb01, ctx0);
    ctx1 = mfma16(pa0, vb10, ctx1); ctx1 = mfma16(pa1, vb11, ctx1);
    __builtin_amdgcn_s_setprio(0);
    __syncthreads();   // barrier2: cur buffer free
    cur ^= 1;
  }

  lsum += __shfl_xor(lsum, 16); lsum += __shfl_xor(lsum, 32);
  plo  += __shfl_xor(plo, 16);  plo  += __shfl_xor(plo, 32);
  phi  += __shfl_xor(phi, 16);  phi  += __shfl_xor(phi, 32);
  if (l < 16) {
    red[wh][0][wq + l] = lsum;
    red[wh][1][wq + l] = plo;
    red[wh][2][wq + l] = phi;
  }
  __syncthreads();
  if (tid < 64) {
    lsum_s[tid] = red[0][0][tid] + red[1][0][tid];
    Tw[(size_t)tid * 288]          = (bf16)(red[0][1][tid] + red[1][1][tid]);
    Tw[(size_t)tid * 288 + 2 * R_] = (bf16)(red[0][2][tid] + red[1][2][tid]);
  }
  // zero pad cols 257..287
  for (int t = tid; t < 64 * 32; t += 512) {
    const int c = t & 31;
    if (c) Tw[(size_t)(t >> 5) * 288 + 256 + c] = (bf16)0.f;
  }
  // zero interior cells whose j is out of range (edge q-tiles only)
  if (q0 < R_ || q0 > S_ - R_ - 64) {
    for (int t = tid; t < 64 * 256; t += 512) {
      const int r = t >> 8, c = t & 255;
      if (c >= 1) {
        const int j = q0 + r + c - R_;
        if (j < 0 || j >= S_) Tw[(size_t)r * 288 + c] = (bf16)0.f;
      }
    }
  }
  __syncthreads();

  // rel-value GEMM: ctx += T(relp)[64][288] @ rvE
#pragma unroll
  for (int ks = 0; ks < 9; ++ks) {
    const bf16x8 pa = *(const bf16x8*)&Tq[ks * 32 + kg8];
    const bf16x8 v0 = *(const bf16x8*)(rvTb + (size_t)(wh * 32 + cl) * 288 + ks * 32 + kg8);
    const bf16x8 v1 = *(const bf16x8*)(rvTb + (size_t)(wh * 32 + 16 + cl) * 288 + ks * 32 + kg8);
    __builtin_amdgcn_s_setprio(1);
    ctx0 = mfma16(pa, v0, ctx0);
    ctx1 = mfma16(pa, v1, ctx1);
    __builtin_amdgcn_s_setprio(0);
  }

#pragma unroll
  for (int reg = 0; reg < 4; ++reg) {
    const int qrow = wq + g * 4 + reg;
    const float invl = 1.f / lsum_s[qrow];
    float* op = out + (size_t)(b * S_ + q0 + qrow) * HID_ + h * 64 + wh * 32;
    op[cl]      = ctx0[reg] * invl;
    op[16 + cl] = ctx1[reg] * invl;
  }
}

extern "C" void kernel_launch(void* const* d_in, const int* in_sizes, int n_in,
                              void* d_out, int out_size, void* d_ws, size_t ws_size,
                              hipStream_t stream)
{
  (void)in_sizes; (void)n_in; (void)out_size; (void)ws_size;
  const float* hidden  = (const float*)d_in[0];
  const float* st_mask = (const float*)d_in[1];
  const float* Wq = (const float*)d_in[2];
  const float* bq = (const float*)d_in[3];
  const float* Wk = (const float*)d_in[4];
  const float* bk = (const float*)d_in[5];
  const float* Wv = (const float*)d_in[6];
  const float* bv = (const float*)d_in[7];
  const float* rkE = (const float*)d_in[8];
  const float* rvE = (const float*)d_in[9];
  float* out = (float*)d_out;

  const size_t per = (size_t)B_ * H_ * S_ * D_;   // 4,194,304 elements
  char* wsb = (char*)d_ws;
  // small tables first
  float* msk2 = (float*)wsb;                               // 16384 B
  bf16*  rkEb = (bf16*)(wsb + 16384);                      // 34816 B
  bf16*  rvTb = (bf16*)(wsb + 16384 + 34816);              // 36864 B
  char*  base1 = wsb + 16384 + 34816 + 36864;              // = wsb + 88064
  bf16* Qh = (bf16*)base1;
  bf16* Ql = Qh + per;
  bf16* Kb = Ql + per;
  bf16* Vt = Kb + per;
  // union region: {Ahg, Alg, Wbg} (prep->qkv) then reused as Tg (attn only)
  bf16* Ahg = Vt + per;
  bf16* Alg = Ahg + per;
  bf16* Wbg = Alg + per;
  bf16* Tg  = Ahg;                                         // 1024 * 64*288 elems

  prep_kernel<<<dim3(1024), 256, 0, stream>>>(
      st_mask, rkE, rvE, hidden, Wq, Wk, Wv, msk2, rkEb, rvTb, Ahg, Alg, Wbg);
  qkv_mfma_kernel<<<dim3(512), 256, 0, stream>>>(
      Ahg, Alg, Wbg, bq, bk, bv, Qh, Ql, Kb, Vt);
  attn_kernel<<<dim3(1024), 512, 0, stream>>>(
      Qh, Ql, Kb, Vt, msk2, rkEb, rvTb, Tg, out);
}

// Round 12
// 184.094 us; speedup vs baseline: 1.2400x; 1.2400x over previous
//
#include <hip/hip_runtime.h>
#include <math.h>

typedef __bf16 bf16;
typedef __bf16 bf16x8 __attribute__((ext_vector_type(8)));
typedef __bf16 bf16x4 __attribute__((ext_vector_type(4)));
typedef float  f32x4  __attribute__((ext_vector_type(4)));

namespace {
constexpr int B_ = 2, S_ = 2048, HID_ = 1024, H_ = 16, D_ = 64, R_ = 128, NREL_ = 257;
constexpr float LOG2E_ = 1.44269504f;
constexpr float QSC_ = 0.125f * LOG2E_;   // 1/sqrt(D) and log2(e), folded into Q
}

static __device__ __forceinline__ f32x4 mfma16(bf16x8 a, bf16x8 b, f32x4 c) {
  return __builtin_amdgcn_mfma_f32_16x16x32_bf16(a, b, c, 0, 0, 0);
}
static __device__ __forceinline__ void split2(float f, bf16 &hi, bf16 &lo) {
  hi = (bf16)f; lo = (bf16)(f - (float)hi);
}
// async global->LDS, 16B per lane. dst must be wave-uniform base (+lane*16 by HW).
static __device__ __forceinline__ void gload16(const bf16* g, bf16* l) {
  __builtin_amdgcn_global_load_lds(
      (const __attribute__((address_space(1))) void*)g,
      (__attribute__((address_space(3))) void*)l, 16, 0, 0);
}

// ---------------- prep: mask, rkE*8, rvE^T, hidden split (Ah/Al), W -> bf16
__global__ __launch_bounds__(256) void prep_kernel(
    const float* __restrict__ st_mask, const float* __restrict__ rkE,
    const float* __restrict__ rvE, const float* __restrict__ hidden,
    const float* __restrict__ Wq, const float* __restrict__ Wk,
    const float* __restrict__ Wv,
    float* __restrict__ msk2, bf16* __restrict__ rkEb, bf16* __restrict__ rvTb,
    bf16* __restrict__ Ahg, bf16* __restrict__ Alg, bf16* __restrict__ Wbg)
{
  const int t0 = blockIdx.x * 256 + threadIdx.x;
  const int NT = gridDim.x * 256;
  for (int t = t0; t < B_ * S_; t += NT)
    msk2[t] = (1.f - st_mask[t]) * -10000.f * LOG2E_;
  for (int t = t0; t < 272 * 64; t += NT) {
    const int bk = t >> 6, d = t & 63;
    rkEb[t] = (bk < NREL_) ? (bf16)(rkE[bk * D_ + d] * 8.0f) : (bf16)0.f;
  }
  for (int t = t0; t < 64 * 288; t += NT) {
    const int d = t / 288, c = t - d * 288;
    rvTb[t] = (c < NREL_) ? (bf16)rvE[c * D_ + d] : (bf16)0.f;
  }
  // hidden split: 4096*1024 f32 -> Ah/Al bf16
  for (int t = t0; t < (B_ * S_ * HID_) / 4; t += NT) {
    const float4 a = ((const float4*)hidden)[t];
    const float av[4] = {a.x, a.y, a.z, a.w};
    bf16x4 h, o;
#pragma unroll
    for (int i = 0; i < 4; ++i) {
      bf16 th, tl;
      split2(av[i], th, tl);
      h[i] = th; o[i] = tl;
    }
    *(bf16x4*)&Ahg[t * 4] = h;
    *(bf16x4*)&Alg[t * 4] = o;
  }
  // W -> bf16 (single), [3][1024][1024]
  for (int t = t0; t < 3 * (HID_ * HID_) / 4; t += NT) {
    const int s = t >> 18, i = t & 262143;
    const float4 wv4 = ((const float4*)(s == 0 ? Wq : s == 1 ? Wk : Wv))[i];
    bf16x4 h;
    h[0] = (bf16)wv4.x; h[1] = (bf16)wv4.y; h[2] = (bf16)wv4.z; h[3] = (bf16)wv4.w;
    *(bf16x4*)&Wbg[s * 1048576 + i * 4] = h;
  }
}

// ---------------- qkv GEMM (passed r10/r11): pure bf16, gload_lds dbuf 2-phase.
// V written TILED [B,H, S/64, D, 64].
__global__ __launch_bounds__(256, 2) void qkv_mfma_kernel(
    const bf16* __restrict__ Ahg, const bf16* __restrict__ Alg,
    const bf16* __restrict__ Wbg,
    const float* __restrict__ bq, const float* __restrict__ bk,
    const float* __restrict__ bv,
    bf16* __restrict__ Qh, bf16* __restrict__ Ql,
    bf16* __restrict__ Kb, bf16* __restrict__ Vt)
{
  const int swz = ((int)blockIdx.x & 7) * 64 + ((int)blockIdx.x >> 3);
  const int m0 = (swz >> 4) * 128;
  const int n0 = (swz & 15) * 64;
  const int tid = threadIdx.x;
  const int l = tid & 63, w = tid >> 6;
  const int cl = l & 15, g = l >> 4;

  __shared__ __align__(16) bf16 AhS[2][4096];
  __shared__ __align__(16) bf16 AlS[2][4096];
  __shared__ __align__(16) bf16 WS[2][3][2048];

  const int r0 = tid >> 2;
  const int csw = (((tid & 3) ^ (r0 & 3)) << 3);
  const size_t aoff0 = (size_t)(m0 + r0) * HID_ + csw;
  const size_t aoff1 = (size_t)(m0 + 64 + r0) * HID_ + csw;
  const size_t woff  = (size_t)(n0 + r0) * HID_ + csw;
  const int wb = w * 512;

  const int rA0 = w * 16 + cl;
  const int eA0 = rA0 * 32 + 8 * (g ^ (rA0 & 3));
  const int eA1 = eA0 + 2048;
  const int eW  = cl * 32 + 8 * (g ^ (cl & 3));

  f32x4 acc[2][3][4];
#pragma unroll
  for (int hf = 0; hf < 2; ++hf)
#pragma unroll
    for (int s = 0; s < 3; ++s)
#pragma unroll
      for (int nf = 0; nf < 4; ++nf)
#pragma unroll
        for (int i = 0; i < 4; ++i) acc[hf][s][nf][i] = 0.f;

  gload16(Ahg + aoff0, &AhS[0][wb]);
  gload16(Ahg + aoff1, &AhS[0][2048 + wb]);
  gload16(Alg + aoff0, &AlS[0][wb]);
  gload16(Alg + aoff1, &AlS[0][2048 + wb]);
  gload16(Wbg + woff,           &WS[0][0][wb]);
  gload16(Wbg + 1048576 + woff, &WS[0][1][wb]);
  gload16(Wbg + 2097152 + woff, &WS[0][2][wb]);
  __syncthreads();

  int cur = 0;
  for (int kt = 0; kt < HID_ / 32; ++kt) {
    if (kt + 1 < HID_ / 32) {
      const size_t ko = (size_t)(kt + 1) * 32;
      bf16* ah = &AhS[cur ^ 1][0]; bf16* al = &AlS[cur ^ 1][0];
      gload16(Ahg + aoff0 + ko, ah + wb);
      gload16(Ahg + aoff1 + ko, ah + 2048 + wb);
      gload16(Alg + aoff0 + ko, al + wb);
      gload16(Alg + aoff1 + ko, al + 2048 + wb);
      gload16(Wbg + woff + ko,           &WS[cur ^ 1][0][wb]);
      gload16(Wbg + 1048576 + woff + ko, &WS[cur ^ 1][1][wb]);
      gload16(Wbg + 2097152 + woff + ko, &WS[cur ^ 1][2][wb]);
    }

    const bf16x8 fah0 = *(const bf16x8*)&AhS[cur][eA0];
    const bf16x8 fah1 = *(const bf16x8*)&AhS[cur][eA1];
    const bf16x8 fal0 = *(const bf16x8*)&AlS[cur][eA0];
    const bf16x8 fal1 = *(const bf16x8*)&AlS[cur][eA1];
#pragma unroll
    for (int s = 0; s < 3; ++s)
#pragma unroll
      for (int nf = 0; nf < 4; ++nf) {
        const bf16x8 fb = *(const bf16x8*)&WS[cur][s][nf * 512 + eW];
        acc[0][s][nf] = mfma16(fah0, fb, acc[0][s][nf]);
        acc[0][s][nf] = mfma16(fal0, fb, acc[0][s][nf]);
        acc[1][s][nf] = mfma16(fah1, fb, acc[1][s][nf]);
        acc[1][s][nf] = mfma16(fal1, fb, acc[1][s][nf]);
      }
    __syncthreads();
    cur ^= 1;
  }

  const float* bs_[3] = {bq, bk, bv};
#pragma unroll
  for (int s = 0; s < 3; ++s)
#pragma unroll
    for (int nf = 0; nf < 4; ++nf) {
      const int n = n0 + nf * 16 + cl;
      const float bias = bs_[s][n];
      const int hd = n >> 6, d = n & 63;
#pragma unroll
      for (int hf = 0; hf < 2; ++hf)
#pragma unroll
        for (int reg = 0; reg < 4; ++reg) {
          const int m = m0 + hf * 64 + w * 16 + g * 4 + reg;
          const int b = m >> 11, sq = m & (S_ - 1);
          const float val = acc[hf][s][nf][reg] + bias;
          if (s == 0) {
            bf16 h, o; split2(val * QSC_, h, o);
            const size_t idx = ((size_t)(b * H_ + hd) * S_ + sq) * D_ + d;
            Qh[idx] = h; Ql[idx] = o;
          } else if (s == 1) {
            Kb[((size_t)(b * H_ + hd) * S_ + sq) * D_ + d] = (bf16)val;
          } else {
            // tiled: [B,H, S/64, D, 64]
            Vt[(((size_t)(b * H_ + hd) * (S_ / 64) + (sq >> 6)) * D_ + d) * 64 + (sq & 63)]
                = (bf16)val;
          }
        }
    }
}

// ---------------- attention v12: r10 structure (T in LDS) + r11's validated
// pieces (full-tile V [64d][64j] 8-chunk swizzle, setprio on MFMA).
__global__ __launch_bounds__(512, 4) void attn_kernel(
    const bf16* __restrict__ Qh, const bf16* __restrict__ Ql,
    const bf16* __restrict__ Kb, const bf16* __restrict__ Vt,
    const float* __restrict__ msk2, const bf16* __restrict__ rkEb,
    const bf16* __restrict__ rvTb, float* __restrict__ out)
{
  const int swz = ((int)blockIdx.x & 7) * 128 + ((int)blockIdx.x >> 3);
  const int qt = swz & 31, h = (swz >> 5) & 15, b = swz >> 9;
  const int q0 = qt * 64;
  const int tid = threadIdx.x;
  const int l = tid & 63, w = tid >> 6;
  const int wq = (w & 3) * 16;
  const int wh = w >> 2;
  const int cl = l & 15, g = l >> 4, kg8 = g * 8;
  const int lq = wq + cl;

  __shared__ __align__(16) bf16 k_s[2][4096];   // [64 j][64 d], 8-chunk swz
  __shared__ __align__(16) bf16 v_s[2][4096];   // [64 d][64 j], 8-chunk swz
  __shared__ __align__(16) bf16 T[64][288];     // rs then relp
  __shared__ __align__(16) bf16 ph[64][72];
  __shared__ float red[2][3][64];
  __shared__ float lsum_s[64];

  const size_t bh = (size_t)(b * H_ + h) * S_;
  const bf16* Kbase = Kb + bh * D_;             // [S][64]
  const bf16* Vbase = Vt + bh * D_;             // tiled [S/64][64][64]
  const float* mbase = msk2 + b * S_;

  // staging source offsets (inverse-swizzled; dest linear)
  const int tKr = tid >> 3;
  const int koff = tKr * 64 + (((tid & 7) ^ (tKr & 7)) << 3);
  const int voff = koff;                        // same [64][64] 8-chunk pattern
  bf16* kdst0 = &k_s[0][w * 512]; bf16* kdst1 = &k_s[1][w * 512];
  bf16* vdst0 = &v_s[0][w * 512]; bf16* vdst1 = &v_s[1][w * 512];

  gload16(Kbase + koff, kdst0);
  gload16(Vbase + voff, vdst0);

  bf16x8 qh0, qh1, ql0, ql1;
  {
    const size_t base = (bh + q0 + lq) * D_ + kg8;
    qh0 = *(const bf16x8*)(Qh + base);
    qh1 = *(const bf16x8*)(Qh + base + 32);
    ql0 = *(const bf16x8*)(Ql + base);
    ql1 = *(const bf16x8*)(Ql + base + 32);
  }

  // rel key scores into T
  {
    const int nt0 = wh ? 9 : 0, ntE = wh ? 17 : 9;
    for (int nt = nt0; nt < ntE; ++nt) {
      f32x4 r; r[0] = r[1] = r[2] = r[3] = 0.f;
      const bf16x8 a0 = *(const bf16x8*)(rkEb + (size_t)(nt * 16 + cl) * 64 + kg8);
      const bf16x8 a1 = *(const bf16x8*)(rkEb + (size_t)(nt * 16 + cl) * 64 + 32 + kg8);
      r = mfma16(a0, qh0, r); r = mfma16(a0, ql0, r);
      r = mfma16(a1, qh1, r); r = mfma16(a1, ql1, r);
      bf16x4 pk;
#pragma unroll
      for (int reg = 0; reg < 4; ++reg) pk[reg] = (bf16)r[reg];
      *(bf16x4*)&T[lq][nt * 16 + g * 4] = pk;
    }
  }
  __syncthreads();   // T ready; kt=0 stage drained

  const float rs_lo = (float)T[lq][0];
  const float rs_hi = (float)T[lq][2 * R_];
  const int qg = q0 + lq;

  f32x4 ctx0, ctx1;
#pragma unroll
  for (int i = 0; i < 4; ++i) { ctx0[i] = 0.f; ctx1[i] = 0.f; }
  float lsum = 0.f, plo = 0.f, phi = 0.f;

  const int r00 = wh * 32 + cl, r10 = wh * 32 + 16 + cl;
  const int e00 = r00 * 64 + 8 * (g ^ (r00 & 7)), e01 = r00 * 64 + 8 * ((4 + g) ^ (r00 & 7));
  const int e10 = r10 * 64 + 8 * (g ^ (r10 & 7)), e11 = r10 * 64 + 8 * ((4 + g) ^ (r10 & 7));
  const int f0  = e00, f0b = e01;               // V uses same [64][64] pattern
  const int f1  = e10, f1b = e11;

  int cur = 0;
  for (int kt = 0; kt < S_ / 64; ++kt) {
    if (kt + 1 < S_ / 64) {
      gload16(Kbase + (size_t)(kt + 1) * 4096 + koff, cur ? kdst0 : kdst1);
      gload16(Vbase + (size_t)(kt + 1) * 4096 + voff, cur ? vdst0 : vdst1);
    }

    const bf16* kc = &k_s[cur][0];
    const bf16x8 a00 = *(const bf16x8*)&kc[e00];
    const bf16x8 a01 = *(const bf16x8*)&kc[e01];
    const bf16x8 a10 = *(const bf16x8*)&kc[e10];
    const bf16x8 a11 = *(const bf16x8*)&kc[e11];

    f32x4 s0, s1;
    s0[0]=s0[1]=s0[2]=s0[3]=0.f; s1[0]=s1[1]=s1[2]=s1[3]=0.f;
    __builtin_amdgcn_s_setprio(1);
    s0 = mfma16(a00, qh0, s0); s0 = mfma16(a00, ql0, s0);
    s0 = mfma16(a01, qh1, s0); s0 = mfma16(a01, ql1, s0);
    s1 = mfma16(a10, qh0, s1); s1 = mfma16(a10, ql0, s1);
    s1 = mfma16(a11, qh1, s1); s1 = mfma16(a11, ql1, s1);
    __builtin_amdgcn_s_setprio(0);

    const int j0 = kt * 64 + wh * 32;
    const float4 mk0 = *(const float4*)(mbase + j0 + g * 4);
    const float4 mk1 = *(const float4*)(mbase + j0 + 16 + g * 4);
    const int dlt = kt * 64 - q0;
    const int mode = (dlt <= -192) ? 0 : (dlt >= 192 ? 1 : 2);

#pragma unroll
    for (int nf = 0; nf < 2; ++nf) {
      const f32x4 sa = nf ? s1 : s0;
      const float4 mkv = nf ? mk1 : mk0;
      const float mks[4] = {mkv.x, mkv.y, mkv.z, mkv.w};
      float p[4];
      if (mode == 0) {
#pragma unroll
        for (int reg = 0; reg < 4; ++reg) p[reg] = exp2f(sa[reg] + rs_lo + mks[reg]);
        plo += (p[0] + p[1]) + (p[2] + p[3]);
      } else if (mode == 1) {
#pragma unroll
        for (int reg = 0; reg < 4; ++reg) p[reg] = exp2f(sa[reg] + rs_hi + mks[reg]);
        phi += (p[0] + p[1]) + (p[2] + p[3]);
      } else {
        const int jb = j0 + nf * 16 + g * 4;
#pragma unroll
        for (int reg = 0; reg < 4; ++reg) {
          const int bkv = jb + reg - qg + R_;
          const int bkc = bkv < 0 ? 0 : (bkv > 2 * R_ ? 2 * R_ : bkv);
          const float pv = exp2f(sa[reg] + (float)T[lq][bkc] + mks[reg]);
          p[reg] = pv;
          if (bkv <= 0)           plo += pv;
          else if (bkv >= 2 * R_) phi += pv;
          else                    T[lq][bkv] = (bf16)pv;   // unique owner cell
        }
      }
      lsum += (p[0] + p[1]) + (p[2] + p[3]);
      bf16x4 pk;
#pragma unroll
      for (int reg = 0; reg < 4; ++reg) pk[reg] = (bf16)p[reg];
      *(bf16x4*)&ph[lq][wh * 32 + nf * 16 + g * 4] = pk;
    }
    __syncthreads();   // barrier1: P written, next stage drained

    const bf16x8 pa0 = *(const bf16x8*)&ph[lq][kg8];
    const bf16x8 pa1 = *(const bf16x8*)&ph[lq][32 + kg8];
    const bf16* vc = &v_s[cur][0];
    const bf16x8 vb00 = *(const bf16x8*)&vc[f0];
    const bf16x8 vb01 = *(const bf16x8*)&vc[f0b];
    const bf16x8 vb10 = *(const bf16x8*)&vc[f1];
    const bf16x8 vb11 = *(const bf16x8*)&vc[f1b];
    __builtin_amdgcn_s_setprio(1);
    ctx0 = mfma16(pa0, vb00, ctx0); ctx0 = mfma16(pa1, vb01, ctx0);
    ctx1 = mfma16(pa0, vb10, ctx1); ctx1 = mfma16(pa1, vb11, ctx1);
    __builtin_amdgcn_s_setprio(0);
    __syncthreads();   // barrier2: cur buffer free
    cur ^= 1;
  }

  lsum += __shfl_xor(lsum, 16); lsum += __shfl_xor(lsum, 32);
  plo  += __shfl_xor(plo, 16);  plo  += __shfl_xor(plo, 32);
  phi  += __shfl_xor(phi, 16);  phi  += __shfl_xor(phi, 32);
  if (l < 16) {
    red[wh][0][wq + l] = lsum;
    red[wh][1][wq + l] = plo;
    red[wh][2][wq + l] = phi;
  }
  __syncthreads();
  if (tid < 64) {
    lsum_s[tid]    = red[0][0][tid] + red[1][0][tid];
    T[tid][0]      = (bf16)(red[0][1][tid] + red[1][1][tid]);
    T[tid][2 * R_] = (bf16)(red[0][2][tid] + red[1][2][tid]);
  }
  for (int t = tid; t < 64 * 32; t += 512) {
    const int c = t & 31;
    if (c) T[t >> 5][256 + c] = (bf16)0.f;
  }
  if (q0 < R_ || q0 > S_ - R_ - 64) {
    for (int t = tid; t < 64 * 256; t += 512) {
      const int r = t >> 8, c = t & 255;
      if (c >= 1) {
        const int j = q0 + r + c - R_;
        if (j < 0 || j >= S_) T[r][c] = (bf16)0.f;
      }
    }
  }
  __syncthreads();

  // rel-value GEMM: ctx += T(relp)[64][288] @ rvE
#pragma unroll
  for (int ks = 0; ks < 9; ++ks) {
    const bf16x8 pa = *(const bf16x8*)&T[lq][ks * 32 + kg8];
    const bf16x8 v0 = *(const bf16x8*)(rvTb + (size_t)(wh * 32 + cl) * 288 + ks * 32 + kg8);
    const bf16x8 v1 = *(const bf16x8*)(rvTb + (size_t)(wh * 32 + 16 + cl) * 288 + ks * 32 + kg8);
    __builtin_amdgcn_s_setprio(1);
    ctx0 = mfma16(pa, v0, ctx0);
    ctx1 = mfma16(pa, v1, ctx1);
    __builtin_amdgcn_s_setprio(0);
  }

#pragma unroll
  for (int reg = 0; reg < 4; ++reg) {
    const int qrow = wq + g * 4 + reg;
    const float invl = 1.f / lsum_s[qrow];
    float* op = out + (size_t)(b * S_ + q0 + qrow) * HID_ + h * 64 + wh * 32;
    op[cl]      = ctx0[reg] * invl;
    op[16 + cl] = ctx1[reg] * invl;
  }
}

extern "C" void kernel_launch(void* const* d_in, const int* in_sizes, int n_in,
                              void* d_out, int out_size, void* d_ws, size_t ws_size,
                              hipStream_t stream)
{
  (void)in_sizes; (void)n_in; (void)out_size; (void)ws_size;
  const float* hidden  = (const float*)d_in[0];
  const float* st_mask = (const float*)d_in[1];
  const float* Wq = (const float*)d_in[2];
  const float* bq = (const float*)d_in[3];
  const float* Wk = (const float*)d_in[4];
  const float* bk = (const float*)d_in[5];
  const float* Wv = (const float*)d_in[6];
  const float* bv = (const float*)d_in[7];
  const float* rkE = (const float*)d_in[8];
  const float* rvE = (const float*)d_in[9];
  float* out = (float*)d_out;

  const size_t per = (size_t)B_ * H_ * S_ * D_;   // 4,194,304 elements
  char* wsb = (char*)d_ws;
  float* msk2 = (float*)wsb;                               // 16384 B
  bf16*  rkEb = (bf16*)(wsb + 16384);                      // 34816 B
  bf16*  rvTb = (bf16*)(wsb + 16384 + 34816);              // 36864 B
  char*  base1 = wsb + 16384 + 34816 + 36864;
  bf16* Qh = (bf16*)base1;
  bf16* Ql = Qh + per;
  bf16* Kb = Ql + per;
  bf16* Vt = Kb + per;
  bf16* Ahg = Vt + per;
  bf16* Alg = Ahg + per;
  bf16* Wbg = Alg + per;

  prep_kernel<<<dim3(1024), 256, 0, stream>>>(
      st_mask, rkE, rvE, hidden, Wq, Wk, Wv, msk2, rkEb, rvTb, Ahg, Alg, Wbg);
  qkv_mfma_kernel<<<dim3(512), 256, 0, stream>>>(
      Ahg, Alg, Wbg, bq, bk, bv, Qh, Ql, Kb, Vt);
  attn_kernel<<<dim3(1024), 512, 0, stream>>>(
      Qh, Ql, Kb, Vt, msk2, rkEb, rvTb, out);
}

// Round 14
// 179.663 us; speedup vs baseline: 1.2706x; 1.0247x over previous
//
#include <hip/hip_runtime.h>
#include <math.h>

typedef __bf16 bf16;
typedef __bf16 bf16x8 __attribute__((ext_vector_type(8)));
typedef __bf16 bf16x4 __attribute__((ext_vector_type(4)));
typedef float  f32x4  __attribute__((ext_vector_type(4)));

namespace {
constexpr int B_ = 2, S_ = 2048, HID_ = 1024, H_ = 16, D_ = 64, R_ = 128, NREL_ = 257;
constexpr float LOG2E_ = 1.44269504f;
constexpr float QSC_ = 0.125f * LOG2E_;   // 1/sqrt(D) and log2(e), folded into Q
}

static __device__ __forceinline__ f32x4 mfma16(bf16x8 a, bf16x8 b, f32x4 c) {
  return __builtin_amdgcn_mfma_f32_16x16x32_bf16(a, b, c, 0, 0, 0);
}
static __device__ __forceinline__ void split2(float f, bf16 &hi, bf16 &lo) {
  hi = (bf16)f; lo = (bf16)(f - (float)hi);
}
// async global->LDS, 16B per lane. dst must be wave-uniform base (+lane*16 by HW).
static __device__ __forceinline__ void gload16(const bf16* g, bf16* l) {
  __builtin_amdgcn_global_load_lds(
      (const __attribute__((address_space(1))) void*)g,
      (__attribute__((address_space(3))) void*)l, 16, 0, 0);
}

// ---------------- prep: mask, rkE*8, rvE^T, hidden split (Ah/Al), W -> bf16
__global__ __launch_bounds__(256) void prep_kernel(
    const float* __restrict__ st_mask, const float* __restrict__ rkE,
    const float* __restrict__ rvE, const float* __restrict__ hidden,
    const float* __restrict__ Wq, const float* __restrict__ Wk,
    const float* __restrict__ Wv,
    float* __restrict__ msk2, bf16* __restrict__ rkEb, bf16* __restrict__ rvTb,
    bf16* __restrict__ Ahg, bf16* __restrict__ Alg, bf16* __restrict__ Wbg)
{
  const int t0 = blockIdx.x * 256 + threadIdx.x;
  const int NT = gridDim.x * 256;
  for (int t = t0; t < B_ * S_; t += NT)
    msk2[t] = (1.f - st_mask[t]) * -10000.f * LOG2E_;
  for (int t = t0; t < 272 * 64; t += NT) {
    const int bk = t >> 6, d = t & 63;
    rkEb[t] = (bk < NREL_) ? (bf16)(rkE[bk * D_ + d] * 8.0f) : (bf16)0.f;
  }
  for (int t = t0; t < 64 * 288; t += NT) {
    const int d = t / 288, c = t - d * 288;
    rvTb[t] = (c < NREL_) ? (bf16)rvE[c * D_ + d] : (bf16)0.f;
  }
  for (int t = t0; t < (B_ * S_ * HID_) / 4; t += NT) {
    const float4 a = ((const float4*)hidden)[t];
    const float av[4] = {a.x, a.y, a.z, a.w};
    bf16x4 h, o;
#pragma unroll
    for (int i = 0; i < 4; ++i) {
      bf16 th, tl;
      split2(av[i], th, tl);
      h[i] = th; o[i] = tl;
    }
    *(bf16x4*)&Ahg[t * 4] = h;
    *(bf16x4*)&Alg[t * 4] = o;
  }
  for (int t = t0; t < 3 * (HID_ * HID_) / 4; t += NT) {
    const int s = t >> 18, i = t & 262143;
    const float4 wv4 = ((const float4*)(s == 0 ? Wq : s == 1 ? Wk : Wv))[i];
    bf16x4 h;
    h[0] = (bf16)wv4.x; h[1] = (bf16)wv4.y; h[2] = (bf16)wv4.z; h[3] = (bf16)wv4.w;
    *(bf16x4*)&Wbg[s * 1048576 + i * 4] = h;
  }
}

// ---------------- qkv GEMM (passed r10-r12). V written TILED [B,H, S/64, D, 64]
// with sigma-permuted columns: col m holds physical j where
// m = (j&32) | j3<<4 | j2<<3 | j4<<2 | (j&3)   (so PV A-operand needs no shuffle).
__global__ __launch_bounds__(256, 2) void qkv_mfma_kernel(
    const bf16* __restrict__ Ahg, const bf16* __restrict__ Alg,
    const bf16* __restrict__ Wbg,
    const float* __restrict__ bq, const float* __restrict__ bk,
    const float* __restrict__ bv,
    bf16* __restrict__ Qh, bf16* __restrict__ Ql,
    bf16* __restrict__ Kb, bf16* __restrict__ Vt)
{
  const int swz = ((int)blockIdx.x & 7) * 64 + ((int)blockIdx.x >> 3);
  const int m0 = (swz >> 4) * 128;
  const int n0 = (swz & 15) * 64;
  const int tid = threadIdx.x;
  const int l = tid & 63, w = tid >> 6;
  const int cl = l & 15, g = l >> 4;

  __shared__ __align__(16) bf16 AhS[2][4096];
  __shared__ __align__(16) bf16 AlS[2][4096];
  __shared__ __align__(16) bf16 WS[2][3][2048];

  const int r0 = tid >> 2;
  const int csw = (((tid & 3) ^ (r0 & 3)) << 3);
  const size_t aoff0 = (size_t)(m0 + r0) * HID_ + csw;
  const size_t aoff1 = (size_t)(m0 + 64 + r0) * HID_ + csw;
  const size_t woff  = (size_t)(n0 + r0) * HID_ + csw;
  const int wb = w * 512;

  const int rA0 = w * 16 + cl;
  const int eA0 = rA0 * 32 + 8 * (g ^ (rA0 & 3));
  const int eA1 = eA0 + 2048;
  const int eW  = cl * 32 + 8 * (g ^ (cl & 3));

  f32x4 acc[2][3][4];
#pragma unroll
  for (int hf = 0; hf < 2; ++hf)
#pragma unroll
    for (int s = 0; s < 3; ++s)
#pragma unroll
      for (int nf = 0; nf < 4; ++nf)
#pragma unroll
        for (int i = 0; i < 4; ++i) acc[hf][s][nf][i] = 0.f;

  gload16(Ahg + aoff0, &AhS[0][wb]);
  gload16(Ahg + aoff1, &AhS[0][2048 + wb]);
  gload16(Alg + aoff0, &AlS[0][wb]);
  gload16(Alg + aoff1, &AlS[0][2048 + wb]);
  gload16(Wbg + woff,           &WS[0][0][wb]);
  gload16(Wbg + 1048576 + woff, &WS[0][1][wb]);
  gload16(Wbg + 2097152 + woff, &WS[0][2][wb]);
  __syncthreads();

  int cur = 0;
  for (int kt = 0; kt < HID_ / 32; ++kt) {
    if (kt + 1 < HID_ / 32) {
      const size_t ko = (size_t)(kt + 1) * 32;
      bf16* ah = &AhS[cur ^ 1][0]; bf16* al = &AlS[cur ^ 1][0];
      gload16(Ahg + aoff0 + ko, ah + wb);
      gload16(Ahg + aoff1 + ko, ah + 2048 + wb);
      gload16(Alg + aoff0 + ko, al + wb);
      gload16(Alg + aoff1 + ko, al + 2048 + wb);
      gload16(Wbg + woff + ko,           &WS[cur ^ 1][0][wb]);
      gload16(Wbg + 1048576 + woff + ko, &WS[cur ^ 1][1][wb]);
      gload16(Wbg + 2097152 + woff + ko, &WS[cur ^ 1][2][wb]);
    }

    const bf16x8 fah0 = *(const bf16x8*)&AhS[cur][eA0];
    const bf16x8 fah1 = *(const bf16x8*)&AhS[cur][eA1];
    const bf16x8 fal0 = *(const bf16x8*)&AlS[cur][eA0];
    const bf16x8 fal1 = *(const bf16x8*)&AlS[cur][eA1];
#pragma unroll
    for (int s = 0; s < 3; ++s)
#pragma unroll
      for (int nf = 0; nf < 4; ++nf) {
        const bf16x8 fb = *(const bf16x8*)&WS[cur][s][nf * 512 + eW];
        acc[0][s][nf] = mfma16(fah0, fb, acc[0][s][nf]);
        acc[0][s][nf] = mfma16(fal0, fb, acc[0][s][nf]);
        acc[1][s][nf] = mfma16(fah1, fb, acc[1][s][nf]);
        acc[1][s][nf] = mfma16(fal1, fb, acc[1][s][nf]);
      }
    __syncthreads();
    cur ^= 1;
  }

  const float* bs_[3] = {bq, bk, bv};
#pragma unroll
  for (int s = 0; s < 3; ++s)
#pragma unroll
    for (int nf = 0; nf < 4; ++nf) {
      const int n = n0 + nf * 16 + cl;
      const float bias = bs_[s][n];
      const int hd = n >> 6, d = n & 63;
#pragma unroll
      for (int hf = 0; hf < 2; ++hf)
#pragma unroll
        for (int reg = 0; reg < 4; ++reg) {
          const int m = m0 + hf * 64 + w * 16 + g * 4 + reg;
          const int b = m >> 11, sq = m & (S_ - 1);
          const float val = acc[hf][s][nf][reg] + bias;
          if (s == 0) {
            bf16 h, o; split2(val * QSC_, h, o);
            const size_t idx = ((size_t)(b * H_ + hd) * S_ + sq) * D_ + d;
            Qh[idx] = h; Ql[idx] = o;
          } else if (s == 1) {
            Kb[((size_t)(b * H_ + hd) * S_ + sq) * D_ + d] = (bf16)val;
          } else {
            // sigma-permuted column within the 64-j tile
            const int jo = sq & 63;
            const int mc = (jo & 32) | (((jo >> 3) & 1) << 4) | (((jo >> 2) & 1) << 3)
                         | (((jo >> 4) & 1) << 2) | (jo & 3);
            Vt[(((size_t)(b * H_ + hd) * (S_ / 64) + (sq >> 6)) * D_ + d) * 64 + mc]
                = (bf16)val;
          }
        }
    }
}

// ---------------- attention v13b: ONE barrier per kt. P never leaves registers
// (sigma-ordered V columns make the lane's packed p's its PV A-operand).
// Wave computes partial ctx[16q][64d] over its own j-half; halves summed once
// at the end via LDS exchange aliased over the K/V buffers.
__global__ __launch_bounds__(512, 4) void attn_kernel(
    const bf16* __restrict__ Qh, const bf16* __restrict__ Ql,
    const bf16* __restrict__ Kb, const bf16* __restrict__ Vt,
    const float* __restrict__ msk2, const bf16* __restrict__ rkEb,
    const bf16* __restrict__ rvTb, float* __restrict__ out)
{
  const int swz = ((int)blockIdx.x & 7) * 128 + ((int)blockIdx.x >> 3);
  const int qt = swz & 31, h = (swz >> 5) & 15, b = swz >> 9;
  const int q0 = qt * 64;
  const int tid = threadIdx.x;
  const int l = tid & 63, w = tid >> 6;
  const int wq = (w & 3) * 16;
  const int wh = w >> 2;
  const int cl = l & 15, g = l >> 4, kg8 = g * 8;
  const int lq = wq + cl;

  // U: K dbuf (2x8KB) + V dbuf (2x8KB) during loop; ctxred [2][64][36] f32 after
  __shared__ __align__(16) unsigned char U[36864];
  __shared__ __align__(16) bf16 T[64][288];     // rs then relp
  __shared__ float red[2][3][64];
  __shared__ float lsum_s[64];

  bf16* kb0 = (bf16*)&U[0];
  bf16* kb1 = (bf16*)&U[8192];
  bf16* vb0 = (bf16*)&U[16384];
  bf16* vb1 = (bf16*)&U[24576];
  float* ctxredf = (float*)&U[0];               // [2][64][36] after loop

  const size_t bh = (size_t)(b * H_ + h) * S_;
  const bf16* Kbase = Kb + bh * D_;             // [S][64]
  const bf16* Vbase = Vt + bh * D_;             // tiled [S/64][64][64], sigma cols
  const float* mbase = msk2 + b * S_;

  // staging source offsets (inverse-XOR-swizzled; dest linear)
  const int tKr = tid >> 3;
  const int koff = tKr * 64 + (((tid & 7) ^ (tKr & 7)) << 3);

  gload16(Kbase + koff, kb0 + w * 512);
  gload16(Vbase + koff, vb0 + w * 512);

  bf16x8 qh0, qh1, ql0, ql1;
  {
    const size_t base = (bh + q0 + lq) * D_ + kg8;
    qh0 = *(const bf16x8*)(Qh + base);
    qh1 = *(const bf16x8*)(Qh + base + 32);
    ql0 = *(const bf16x8*)(Ql + base);
    ql1 = *(const bf16x8*)(Ql + base + 32);
  }

  // rel key scores into T
  {
    const int nt0 = wh ? 9 : 0, ntE = wh ? 17 : 9;
    for (int nt = nt0; nt < ntE; ++nt) {
      f32x4 r; r[0] = r[1] = r[2] = r[3] = 0.f;
      const bf16x8 a0 = *(const bf16x8*)(rkEb + (size_t)(nt * 16 + cl) * 64 + kg8);
      const bf16x8 a1 = *(const bf16x8*)(rkEb + (size_t)(nt * 16 + cl) * 64 + 32 + kg8);
      r = mfma16(a0, qh0, r); r = mfma16(a0, ql0, r);
      r = mfma16(a1, qh1, r); r = mfma16(a1, ql1, r);
      bf16x4 pk;
#pragma unroll
      for (int reg = 0; reg < 4; ++reg) pk[reg] = (bf16)r[reg];
      *(bf16x4*)&T[lq][nt * 16 + g * 4] = pk;
    }
  }
  __syncthreads();   // T ready; kt=0 stage drained

  const float rs_lo = (float)T[lq][0];
  const float rs_hi = (float)T[lq][2 * R_];
  const int qg = q0 + lq;

  f32x4 ctx[4];
#pragma unroll
  for (int nf = 0; nf < 4; ++nf) { ctx[nf][0]=0.f; ctx[nf][1]=0.f; ctx[nf][2]=0.f; ctx[nf][3]=0.f; }
  float lsum = 0.f, plo = 0.f, phi = 0.f;

  const int r00 = wh * 32 + cl, r10 = wh * 32 + 16 + cl;
  const int e00 = r00 * 64 + 8 * (g ^ (r00 & 7)), e01 = r00 * 64 + 8 * ((4 + g) ^ (r00 & 7));
  const int e10 = r10 * 64 + 8 * (g ^ (r10 & 7)), e11 = r10 * 64 + 8 * ((4 + g) ^ (r10 & 7));
  // PV B-operand offsets: row = nf*16+cl (d), chunk = (4*wh+g) ^ (row&7)
  int fv0, fv1, fv2, fv3;
  {
    const int rd0 = 0 * 16 + cl, rd1 = 1 * 16 + cl, rd2 = 2 * 16 + cl, rd3 = 3 * 16 + cl;
    fv0 = rd0 * 64 + 8 * ((4 * wh + g) ^ (rd0 & 7));
    fv1 = rd1 * 64 + 8 * ((4 * wh + g) ^ (rd1 & 7));
    fv2 = rd2 * 64 + 8 * ((4 * wh + g) ^ (rd2 & 7));
    fv3 = rd3 * 64 + 8 * ((4 * wh + g) ^ (rd3 & 7));
  }

  int cur = 0;
  for (int kt = 0; kt < S_ / 64; ++kt) {
    if (kt + 1 < S_ / 64) {
      gload16(Kbase + (size_t)(kt + 1) * 4096 + koff, (cur ? kb0 : kb1) + w * 512);
      gload16(Vbase + (size_t)(kt + 1) * 4096 + koff, (cur ? vb0 : vb1) + w * 512);
    }

    const bf16* kc = cur ? kb1 : kb0;
    const bf16x8 a00 = *(const bf16x8*)&kc[e00];
    const bf16x8 a01 = *(const bf16x8*)&kc[e01];
    const bf16x8 a10 = *(const bf16x8*)&kc[e10];
    const bf16x8 a11 = *(const bf16x8*)&kc[e11];

    f32x4 s0, s1;
    s0[0]=s0[1]=s0[2]=s0[3]=0.f; s1[0]=s1[1]=s1[2]=s1[3]=0.f;
    __builtin_amdgcn_s_setprio(1);
    s0 = mfma16(a00, qh0, s0); s0 = mfma16(a00, ql0, s0);
    s0 = mfma16(a01, qh1, s0); s0 = mfma16(a01, ql1, s0);
    s1 = mfma16(a10, qh0, s1); s1 = mfma16(a10, ql0, s1);
    s1 = mfma16(a11, qh1, s1); s1 = mfma16(a11, ql1, s1);
    __builtin_amdgcn_s_setprio(0);

    const int j0 = kt * 64 + wh * 32;
    const float4 mk0 = *(const float4*)(mbase + j0 + g * 4);
    const float4 mk1 = *(const float4*)(mbase + j0 + 16 + g * 4);
    const int dlt = kt * 64 - q0;
    const int mode = (dlt <= -192) ? 0 : (dlt >= 192 ? 1 : 2);

    bf16x4 pk0, pk1;
#pragma unroll
    for (int nf = 0; nf < 2; ++nf) {
      const f32x4 sa = nf ? s1 : s0;
      const float4 mkv = nf ? mk1 : mk0;
      const float mks[4] = {mkv.x, mkv.y, mkv.z, mkv.w};
      float p[4];
      if (mode == 0) {
#pragma unroll
        for (int reg = 0; reg < 4; ++reg) p[reg] = exp2f(sa[reg] + rs_lo + mks[reg]);
        plo += (p[0] + p[1]) + (p[2] + p[3]);
      } else if (mode == 1) {
#pragma unroll
        for (int reg = 0; reg < 4; ++reg) p[reg] = exp2f(sa[reg] + rs_hi + mks[reg]);
        phi += (p[0] + p[1]) + (p[2] + p[3]);
      } else {
        const int jb = j0 + nf * 16 + g * 4;
#pragma unroll
        for (int reg = 0; reg < 4; ++reg) {
          const int bkv = jb + reg - qg + R_;
          const int bkc = bkv < 0 ? 0 : (bkv > 2 * R_ ? 2 * R_ : bkv);
          const float pv = exp2f(sa[reg] + (float)T[lq][bkc] + mks[reg]);
          p[reg] = pv;
          if (bkv <= 0)           plo += pv;
          else if (bkv >= 2 * R_) phi += pv;
          else                    T[lq][bkv] = (bf16)pv;   // unique owner cell
        }
      }
      lsum += (p[0] + p[1]) + (p[2] + p[3]);
      bf16x4 pk;
#pragma unroll
      for (int reg = 0; reg < 4; ++reg) pk[reg] = (bf16)p[reg];
      if (nf == 0) pk0 = pk; else pk1 = pk;
    }

    // PV: A-operand = packed p's (sigma ordering makes this exact)
    bf16x8 pa;
    pa[0] = pk0[0]; pa[1] = pk0[1]; pa[2] = pk0[2]; pa[3] = pk0[3];
    pa[4] = pk1[0]; pa[5] = pk1[1]; pa[6] = pk1[2]; pa[7] = pk1[3];
    const bf16* vc = cur ? vb1 : vb0;
    __builtin_amdgcn_s_setprio(1);
    ctx[0] = mfma16(pa, *(const bf16x8*)&vc[fv0], ctx[0]);
    ctx[1] = mfma16(pa, *(const bf16x8*)&vc[fv1], ctx[1]);
    ctx[2] = mfma16(pa, *(const bf16x8*)&vc[fv2], ctx[2]);
    ctx[3] = mfma16(pa, *(const bf16x8*)&vc[fv3], ctx[3]);
    __builtin_amdgcn_s_setprio(0);
    __syncthreads();   // single barrier: buffers free + next stage drained
    cur ^= 1;
  }

  // lane-group reductions (q fixed per lane)
  lsum += __shfl_xor(lsum, 16); lsum += __shfl_xor(lsum, 32);
  plo  += __shfl_xor(plo, 16);  plo  += __shfl_xor(plo, 32);
  phi  += __shfl_xor(phi, 16);  phi  += __shfl_xor(phi, 32);
  if (l < 16) {
    red[wh][0][wq + l] = lsum;
    red[wh][1][wq + l] = plo;
    red[wh][2][wq + l] = phi;
  }
  __syncthreads();   // red ready; all loop LDS reads done (U reusable)

  // exchange non-kept ctx halves via U: writer slot [wh]
  {
    const int nfs = wh ? 0 : 2;
#pragma unroll
    for (int k2 = 0; k2 < 2; ++k2)
#pragma unroll
      for (int reg = 0; reg < 4; ++reg)
        ctxredf[((wh * 64) + wq + g * 4 + reg) * 36 + k2 * 16 + cl] = ctx[nfs + k2][reg];
  }
  if (tid < 64) {
    lsum_s[tid]    = red[0][0][tid] + red[1][0][tid];
    T[tid][0]      = (bf16)(red[0][1][tid] + red[1][1][tid]);
    T[tid][2 * R_] = (bf16)(red[0][2][tid] + red[1][2][tid]);
  }
  for (int t = tid; t < 64 * 32; t += 512) {
    const int c = t & 31;
    if (c) T[t >> 5][256 + c] = (bf16)0.f;
  }
  if (q0 < R_ || q0 > S_ - R_ - 64) {
    for (int t = tid; t < 64 * 256; t += 512) {
      const int r = t >> 8, c = t & 255;
      if (c >= 1) {
        const int j = q0 + r + c - R_;
        if (j < 0 || j >= S_) T[r][c] = (bf16)0.f;
      }
    }
  }
  __syncthreads();

  // complete kept halves with peer's partials
  const int nfa = wh ? 2 : 0;
  f32x4 cx0 = ctx[nfa], cx1 = ctx[nfa + 1];
#pragma unroll
  for (int reg = 0; reg < 4; ++reg) {
    cx0[reg] += ctxredf[(((wh ^ 1) * 64) + wq + g * 4 + reg) * 36 + cl];
    cx1[reg] += ctxredf[(((wh ^ 1) * 64) + wq + g * 4 + reg) * 36 + 16 + cl];
  }

  // rel-value GEMM: ctx += T(relp)[64][288] @ rvE
#pragma unroll
  for (int ks = 0; ks < 9; ++ks) {
    const bf16x8 pa = *(const bf16x8*)&T[lq][ks * 32 + kg8];
    const bf16x8 v0 = *(const bf16x8*)(rvTb + (size_t)(wh * 32 + cl) * 288 + ks * 32 + kg8);
    const bf16x8 v1 = *(const bf16x8*)(rvTb + (size_t)(wh * 32 + 16 + cl) * 288 + ks * 32 + kg8);
    __builtin_amdgcn_s_setprio(1);
    cx0 = mfma16(pa, v0, cx0);
    cx1 = mfma16(pa, v1, cx1);
    __builtin_amdgcn_s_setprio(0);
  }

#pragma unroll
  for (int reg = 0; reg < 4; ++reg) {
    const int qrow = wq + g * 4 + reg;
    const float invl = 1.f / lsum_s[qrow];
    float* op = out + (size_t)(b * S_ + q0 + qrow) * HID_ + h * 64 + wh * 32;
    op[cl]      = cx0[reg] * invl;
    op[16 + cl] = cx1[reg] * invl;
  }
}

extern "C" void kernel_launch(void* const* d_in, const int* in_sizes, int n_in,
                              void* d_out, int out_size, void* d_ws, size_t ws_size,
                              hipStream_t stream)
{
  (void)in_sizes; (void)n_in; (void)out_size; (void)ws_size;
  const float* hidden  = (const float*)d_in[0];
  const float* st_mask = (const float*)d_in[1];
  const float* Wq = (const float*)d_in[2];
  const float* bq = (const float*)d_in[3];
  const float* Wk = (const float*)d_in[4];
  const float* bk = (const float*)d_in[5];
  const float* Wv = (const float*)d_in[6];
  const float* bv = (const float*)d_in[7];
  const float* rkE = (const float*)d_in[8];
  const float* rvE = (const float*)d_in[9];
  float* out = (float*)d_out;

  const size_t per = (size_t)B_ * H_ * S_ * D_;   // 4,194,304 elements
  char* wsb = (char*)d_ws;
  float* msk2 = (float*)wsb;                               // 16384 B
  bf16*  rkEb = (bf16*)(wsb + 16384);                      // 34816 B
  bf16*  rvTb = (bf16*)(wsb + 16384 + 34816);              // 36864 B
  char*  base1 = wsb + 16384 + 34816 + 36864;
  bf16* Qh = (bf16*)base1;
  bf16* Ql = Qh + per;
  bf16* Kb = Ql + per;
  bf16* Vt = Kb + per;
  bf16* Ahg = Vt + per;
  bf16* Alg = Ahg + per;
  bf16* Wbg = Alg + per;

  prep_kernel<<<dim3(1024), 256, 0, stream>>>(
      st_mask, rkE, rvE, hidden, Wq, Wk, Wv, msk2, rkEb, rvTb, Ahg, Alg, Wbg);
  qkv_mfma_kernel<<<dim3(512), 256, 0, stream>>>(
      Ahg, Alg, Wbg, bq, bk, bv, Qh, Ql, Kb, Vt);
  attn_kernel<<<dim3(1024), 512, 0, stream>>>(
      Qh, Ql, Kb, Vt, msk2, rkEb, rvTb, out);
}

// Round 15
// 166.670 us; speedup vs baseline: 1.3696x; 1.0780x over previous
//
#include <hip/hip_runtime.h>
#include <math.h>

typedef __bf16 bf16;
typedef __bf16 bf16x8 __attribute__((ext_vector_type(8)));
typedef __bf16 bf16x4 __attribute__((ext_vector_type(4)));
typedef float  f32x4  __attribute__((ext_vector_type(4)));

namespace {
constexpr int B_ = 2, S_ = 2048, HID_ = 1024, H_ = 16, D_ = 64, R_ = 128, NREL_ = 257;
constexpr float LOG2E_ = 1.44269504f;
constexpr float QSC_ = 0.125f * LOG2E_;   // 1/sqrt(D) and log2(e), folded into Q
}

static __device__ __forceinline__ f32x4 mfma16(bf16x8 a, bf16x8 b, f32x4 c) {
  return __builtin_amdgcn_mfma_f32_16x16x32_bf16(a, b, c, 0, 0, 0);
}
static __device__ __forceinline__ void split2(float f, bf16 &hi, bf16 &lo) {
  hi = (bf16)f; lo = (bf16)(f - (float)hi);
}
static __device__ __forceinline__ float fexp2(float x) {
  return __builtin_amdgcn_exp2f(x);   // raw v_exp_f32 (ocml wrapper costs ~6 VALU)
}
// async global->LDS, 16B per lane. dst must be wave-uniform base (+lane*16 by HW).
static __device__ __forceinline__ void gload16(const bf16* g, bf16* l) {
  __builtin_amdgcn_global_load_lds(
      (const __attribute__((address_space(1))) void*)g,
      (__attribute__((address_space(3))) void*)l, 16, 0, 0);
}

// ---------------- prep: mask, rkE*8, rvE^T, hidden split (Ah/Al), W -> bf16
__global__ __launch_bounds__(256) void prep_kernel(
    const float* __restrict__ st_mask, const float* __restrict__ rkE,
    const float* __restrict__ rvE, const float* __restrict__ hidden,
    const float* __restrict__ Wq, const float* __restrict__ Wk,
    const float* __restrict__ Wv,
    float* __restrict__ msk2, bf16* __restrict__ rkEb, bf16* __restrict__ rvTb,
    bf16* __restrict__ Ahg, bf16* __restrict__ Alg, bf16* __restrict__ Wbg)
{
  const int t0 = blockIdx.x * 256 + threadIdx.x;
  const int NT = gridDim.x * 256;
  for (int t = t0; t < B_ * S_; t += NT)
    msk2[t] = (1.f - st_mask[t]) * -10000.f * LOG2E_;
  for (int t = t0; t < 272 * 64; t += NT) {
    const int bk = t >> 6, d = t & 63;
    rkEb[t] = (bk < NREL_) ? (bf16)(rkE[bk * D_ + d] * 8.0f) : (bf16)0.f;
  }
  for (int t = t0; t < 64 * 288; t += NT) {
    const int d = t / 288, c = t - d * 288;
    rvTb[t] = (c < NREL_) ? (bf16)rvE[c * D_ + d] : (bf16)0.f;
  }
  for (int t = t0; t < (B_ * S_ * HID_) / 4; t += NT) {
    const float4 a = ((const float4*)hidden)[t];
    const float av[4] = {a.x, a.y, a.z, a.w};
    bf16x4 h, o;
#pragma unroll
    for (int i = 0; i < 4; ++i) {
      bf16 th, tl;
      split2(av[i], th, tl);
      h[i] = th; o[i] = tl;
    }
    *(bf16x4*)&Ahg[t * 4] = h;
    *(bf16x4*)&Alg[t * 4] = o;
  }
  for (int t = t0; t < 3 * (HID_ * HID_) / 4; t += NT) {
    const int s = t >> 18, i = t & 262143;
    const float4 wv4 = ((const float4*)(s == 0 ? Wq : s == 1 ? Wk : Wv))[i];
    bf16x4 h;
    h[0] = (bf16)wv4.x; h[1] = (bf16)wv4.y; h[2] = (bf16)wv4.z; h[3] = (bf16)wv4.w;
    *(bf16x4*)&Wbg[s * 1048576 + i * 4] = h;
  }
}

// ---------------- qkv GEMM (passed r10-r14). V written TILED [B,H, S/64, D, 64]
// with sigma-permuted columns: col m holds physical j where
// m = (j&32) | j3<<4 | j2<<3 | j4<<2 | (j&3)   (so PV A-operand needs no shuffle).
__global__ __launch_bounds__(256, 2) void qkv_mfma_kernel(
    const bf16* __restrict__ Ahg, const bf16* __restrict__ Alg,
    const bf16* __restrict__ Wbg,
    const float* __restrict__ bq, const float* __restrict__ bk,
    const float* __restrict__ bv,
    bf16* __restrict__ Qh, bf16* __restrict__ Ql,
    bf16* __restrict__ Kb, bf16* __restrict__ Vt)
{
  const int swz = ((int)blockIdx.x & 7) * 64 + ((int)blockIdx.x >> 3);
  const int m0 = (swz >> 4) * 128;
  const int n0 = (swz & 15) * 64;
  const int tid = threadIdx.x;
  const int l = tid & 63, w = tid >> 6;
  const int cl = l & 15, g = l >> 4;

  __shared__ __align__(16) bf16 AhS[2][4096];
  __shared__ __align__(16) bf16 AlS[2][4096];
  __shared__ __align__(16) bf16 WS[2][3][2048];

  const int r0 = tid >> 2;
  const int csw = (((tid & 3) ^ (r0 & 3)) << 3);
  const size_t aoff0 = (size_t)(m0 + r0) * HID_ + csw;
  const size_t aoff1 = (size_t)(m0 + 64 + r0) * HID_ + csw;
  const size_t woff  = (size_t)(n0 + r0) * HID_ + csw;
  const int wb = w * 512;

  const int rA0 = w * 16 + cl;
  const int eA0 = rA0 * 32 + 8 * (g ^ (rA0 & 3));
  const int eA1 = eA0 + 2048;
  const int eW  = cl * 32 + 8 * (g ^ (cl & 3));

  f32x4 acc[2][3][4];
#pragma unroll
  for (int hf = 0; hf < 2; ++hf)
#pragma unroll
    for (int s = 0; s < 3; ++s)
#pragma unroll
      for (int nf = 0; nf < 4; ++nf)
#pragma unroll
        for (int i = 0; i < 4; ++i) acc[hf][s][nf][i] = 0.f;

  gload16(Ahg + aoff0, &AhS[0][wb]);
  gload16(Ahg + aoff1, &AhS[0][2048 + wb]);
  gload16(Alg + aoff0, &AlS[0][wb]);
  gload16(Alg + aoff1, &AlS[0][2048 + wb]);
  gload16(Wbg + woff,           &WS[0][0][wb]);
  gload16(Wbg + 1048576 + woff, &WS[0][1][wb]);
  gload16(Wbg + 2097152 + woff, &WS[0][2][wb]);
  __syncthreads();

  int cur = 0;
  for (int kt = 0; kt < HID_ / 32; ++kt) {
    if (kt + 1 < HID_ / 32) {
      const size_t ko = (size_t)(kt + 1) * 32;
      bf16* ah = &AhS[cur ^ 1][0]; bf16* al = &AlS[cur ^ 1][0];
      gload16(Ahg + aoff0 + ko, ah + wb);
      gload16(Ahg + aoff1 + ko, ah + 2048 + wb);
      gload16(Alg + aoff0 + ko, al + wb);
      gload16(Alg + aoff1 + ko, al + 2048 + wb);
      gload16(Wbg + woff + ko,           &WS[cur ^ 1][0][wb]);
      gload16(Wbg + 1048576 + woff + ko, &WS[cur ^ 1][1][wb]);
      gload16(Wbg + 2097152 + woff + ko, &WS[cur ^ 1][2][wb]);
    }

    const bf16x8 fah0 = *(const bf16x8*)&AhS[cur][eA0];
    const bf16x8 fah1 = *(const bf16x8*)&AhS[cur][eA1];
    const bf16x8 fal0 = *(const bf16x8*)&AlS[cur][eA0];
    const bf16x8 fal1 = *(const bf16x8*)&AlS[cur][eA1];
#pragma unroll
    for (int s = 0; s < 3; ++s)
#pragma unroll
      for (int nf = 0; nf < 4; ++nf) {
        const bf16x8 fb = *(const bf16x8*)&WS[cur][s][nf * 512 + eW];
        acc[0][s][nf] = mfma16(fah0, fb, acc[0][s][nf]);
        acc[0][s][nf] = mfma16(fal0, fb, acc[0][s][nf]);
        acc[1][s][nf] = mfma16(fah1, fb, acc[1][s][nf]);
        acc[1][s][nf] = mfma16(fal1, fb, acc[1][s][nf]);
      }
    __syncthreads();
    cur ^= 1;
  }

  const float* bs_[3] = {bq, bk, bv};
#pragma unroll
  for (int s = 0; s < 3; ++s)
#pragma unroll
    for (int nf = 0; nf < 4; ++nf) {
      const int n = n0 + nf * 16 + cl;
      const float bias = bs_[s][n];
      const int hd = n >> 6, d = n & 63;
#pragma unroll
      for (int hf = 0; hf < 2; ++hf)
#pragma unroll
        for (int reg = 0; reg < 4; ++reg) {
          const int m = m0 + hf * 64 + w * 16 + g * 4 + reg;
          const int b = m >> 11, sq = m & (S_ - 1);
          const float val = acc[hf][s][nf][reg] + bias;
          if (s == 0) {
            bf16 h, o; split2(val * QSC_, h, o);
            const size_t idx = ((size_t)(b * H_ + hd) * S_ + sq) * D_ + d;
            Qh[idx] = h; Ql[idx] = o;
          } else if (s == 1) {
            Kb[((size_t)(b * H_ + hd) * S_ + sq) * D_ + d] = (bf16)val;
          } else {
            const int jo = sq & 63;
            const int mc = (jo & 32) | (((jo >> 3) & 1) << 4) | (((jo >> 2) & 1) << 3)
                         | (((jo >> 4) & 1) << 2) | (jo & 3);
            Vt[(((size_t)(b * H_ + hd) * (S_ / 64) + (sq >> 6)) * D_ + d) * 64 + mc]
                = (bf16)val;
          }
        }
    }
}

// ---------------- attention v15: v13b + native v_exp_f32 (softmax VALU thinned)
// + shufflevector pa concat. One barrier/kt, P in registers.
__global__ __launch_bounds__(512, 4) void attn_kernel(
    const bf16* __restrict__ Qh, const bf16* __restrict__ Ql,
    const bf16* __restrict__ Kb, const bf16* __restrict__ Vt,
    const float* __restrict__ msk2, const bf16* __restrict__ rkEb,
    const bf16* __restrict__ rvTb, float* __restrict__ out)
{
  const int swz = ((int)blockIdx.x & 7) * 128 + ((int)blockIdx.x >> 3);
  const int qt = swz & 31, h = (swz >> 5) & 15, b = swz >> 9;
  const int q0 = qt * 64;
  const int tid = threadIdx.x;
  const int l = tid & 63, w = tid >> 6;
  const int wq = (w & 3) * 16;
  const int wh = w >> 2;
  const int cl = l & 15, g = l >> 4, kg8 = g * 8;
  const int lq = wq + cl;

  // U: K dbuf (2x8KB) + V dbuf (2x8KB) during loop; ctxred [2][64][36] f32 after
  __shared__ __align__(16) unsigned char U[36864];
  __shared__ __align__(16) bf16 T[64][288];     // rs then relp
  __shared__ float red[2][3][64];
  __shared__ float lsum_s[64];

  bf16* kb0 = (bf16*)&U[0];
  bf16* kb1 = (bf16*)&U[8192];
  bf16* vb0 = (bf16*)&U[16384];
  bf16* vb1 = (bf16*)&U[24576];
  float* ctxredf = (float*)&U[0];               // [2][64][36] after loop

  const size_t bh = (size_t)(b * H_ + h) * S_;
  const bf16* Kbase = Kb + bh * D_;             // [S][64]
  const bf16* Vbase = Vt + bh * D_;             // tiled [S/64][64][64], sigma cols
  const float* mbase = msk2 + b * S_;

  const int tKr = tid >> 3;
  const int koff = tKr * 64 + (((tid & 7) ^ (tKr & 7)) << 3);

  gload16(Kbase + koff, kb0 + w * 512);
  gload16(Vbase + koff, vb0 + w * 512);

  bf16x8 qh0, qh1, ql0, ql1;
  {
    const size_t base = (bh + q0 + lq) * D_ + kg8;
    qh0 = *(const bf16x8*)(Qh + base);
    qh1 = *(const bf16x8*)(Qh + base + 32);
    ql0 = *(const bf16x8*)(Ql + base);
    ql1 = *(const bf16x8*)(Ql + base + 32);
  }

  // rel key scores into T
  {
    const int nt0 = wh ? 9 : 0, ntE = wh ? 17 : 9;
    for (int nt = nt0; nt < ntE; ++nt) {
      f32x4 r; r[0] = r[1] = r[2] = r[3] = 0.f;
      const bf16x8 a0 = *(const bf16x8*)(rkEb + (size_t)(nt * 16 + cl) * 64 + kg8);
      const bf16x8 a1 = *(const bf16x8*)(rkEb + (size_t)(nt * 16 + cl) * 64 + 32 + kg8);
      r = mfma16(a0, qh0, r); r = mfma16(a0, ql0, r);
      r = mfma16(a1, qh1, r); r = mfma16(a1, ql1, r);
      bf16x4 pk;
#pragma unroll
      for (int reg = 0; reg < 4; ++reg) pk[reg] = (bf16)r[reg];
      *(bf16x4*)&T[lq][nt * 16 + g * 4] = pk;
    }
  }
  __syncthreads();   // T ready; kt=0 stage drained

  const float rs_lo = (float)T[lq][0];
  const float rs_hi = (float)T[lq][2 * R_];
  const int qg = q0 + lq;

  f32x4 ctx[4];
#pragma unroll
  for (int nf = 0; nf < 4; ++nf) { ctx[nf][0]=0.f; ctx[nf][1]=0.f; ctx[nf][2]=0.f; ctx[nf][3]=0.f; }
  float lsum = 0.f, plo = 0.f, phi = 0.f;

  const int r00 = wh * 32 + cl, r10 = wh * 32 + 16 + cl;
  const int e00 = r00 * 64 + 8 * (g ^ (r00 & 7)), e01 = r00 * 64 + 8 * ((4 + g) ^ (r00 & 7));
  const int e10 = r10 * 64 + 8 * (g ^ (r10 & 7)), e11 = r10 * 64 + 8 * ((4 + g) ^ (r10 & 7));
  int fv0, fv1, fv2, fv3;
  {
    const int rd0 = 0 * 16 + cl, rd1 = 1 * 16 + cl, rd2 = 2 * 16 + cl, rd3 = 3 * 16 + cl;
    fv0 = rd0 * 64 + 8 * ((4 * wh + g) ^ (rd0 & 7));
    fv1 = rd1 * 64 + 8 * ((4 * wh + g) ^ (rd1 & 7));
    fv2 = rd2 * 64 + 8 * ((4 * wh + g) ^ (rd2 & 7));
    fv3 = rd3 * 64 + 8 * ((4 * wh + g) ^ (rd3 & 7));
  }

  int cur = 0;
  for (int kt = 0; kt < S_ / 64; ++kt) {
    if (kt + 1 < S_ / 64) {
      gload16(Kbase + (size_t)(kt + 1) * 4096 + koff, (cur ? kb0 : kb1) + w * 512);
      gload16(Vbase + (size_t)(kt + 1) * 4096 + koff, (cur ? vb0 : vb1) + w * 512);
    }

    const bf16* kc = cur ? kb1 : kb0;
    const bf16x8 a00 = *(const bf16x8*)&kc[e00];
    const bf16x8 a01 = *(const bf16x8*)&kc[e01];
    const bf16x8 a10 = *(const bf16x8*)&kc[e10];
    const bf16x8 a11 = *(const bf16x8*)&kc[e11];

    f32x4 s0, s1;
    s0[0]=s0[1]=s0[2]=s0[3]=0.f; s1[0]=s1[1]=s1[2]=s1[3]=0.f;
    __builtin_amdgcn_s_setprio(1);
    s0 = mfma16(a00, qh0, s0); s0 = mfma16(a00, ql0, s0);
    s0 = mfma16(a01, qh1, s0); s0 = mfma16(a01, ql1, s0);
    s1 = mfma16(a10, qh0, s1); s1 = mfma16(a10, ql0, s1);
    s1 = mfma16(a11, qh1, s1); s1 = mfma16(a11, ql1, s1);
    __builtin_amdgcn_s_setprio(0);

    const int j0 = kt * 64 + wh * 32;
    const float4 mk0 = *(const float4*)(mbase + j0 + g * 4);
    const float4 mk1 = *(const float4*)(mbase + j0 + 16 + g * 4);
    const int dlt = kt * 64 - q0;
    const int mode = (dlt <= -192) ? 0 : (dlt >= 192 ? 1 : 2);

    bf16x4 pk0, pk1;
#pragma unroll
    for (int nf = 0; nf < 2; ++nf) {
      const f32x4 sa = nf ? s1 : s0;
      const float4 mkv = nf ? mk1 : mk0;
      const float mks[4] = {mkv.x, mkv.y, mkv.z, mkv.w};
      float p[4];
      if (mode == 0) {
#pragma unroll
        for (int reg = 0; reg < 4; ++reg) p[reg] = fexp2(sa[reg] + rs_lo + mks[reg]);
        plo += (p[0] + p[1]) + (p[2] + p[3]);
      } else if (mode == 1) {
#pragma unroll
        for (int reg = 0; reg < 4; ++reg) p[reg] = fexp2(sa[reg] + rs_hi + mks[reg]);
        phi += (p[0] + p[1]) + (p[2] + p[3]);
      } else {
        const int jb = j0 + nf * 16 + g * 4;
#pragma unroll
        for (int reg = 0; reg < 4; ++reg) {
          const int bkv = jb + reg - qg + R_;
          const int bkc = bkv < 0 ? 0 : (bkv > 2 * R_ ? 2 * R_ : bkv);
          const float pv = fexp2(sa[reg] + (float)T[lq][bkc] + mks[reg]);
          p[reg] = pv;
          if (bkv <= 0)           plo += pv;
          else if (bkv >= 2 * R_) phi += pv;
          else                    T[lq][bkv] = (bf16)pv;   // unique owner cell
        }
      }
      lsum += (p[0] + p[1]) + (p[2] + p[3]);
      bf16x4 pk;
#pragma unroll
      for (int reg = 0; reg < 4; ++reg) pk[reg] = (bf16)p[reg];
      if (nf == 0) pk0 = pk; else pk1 = pk;
    }

    // PV: A-operand = packed p's (sigma ordering makes this exact)
    const bf16x8 pa = __builtin_shufflevector(pk0, pk1, 0, 1, 2, 3, 4, 5, 6, 7);
    const bf16* vc = cur ? vb1 : vb0;
    __builtin_amdgcn_s_setprio(1);
    ctx[0] = mfma16(pa, *(const bf16x8*)&vc[fv0], ctx[0]);
    ctx[1] = mfma16(pa, *(const bf16x8*)&vc[fv1], ctx[1]);
    ctx[2] = mfma16(pa, *(const bf16x8*)&vc[fv2], ctx[2]);
    ctx[3] = mfma16(pa, *(const bf16x8*)&vc[fv3], ctx[3]);
    __builtin_amdgcn_s_setprio(0);
    __syncthreads();   // single barrier: buffers free + next stage drained
    cur ^= 1;
  }

  // lane-group reductions (q fixed per lane)
  lsum += __shfl_xor(lsum, 16); lsum += __shfl_xor(lsum, 32);
  plo  += __shfl_xor(plo, 16);  plo  += __shfl_xor(plo, 32);
  phi  += __shfl_xor(phi, 16);  phi  += __shfl_xor(phi, 32);
  if (l < 16) {
    red[wh][0][wq + l] = lsum;
    red[wh][1][wq + l] = plo;
    red[wh][2][wq + l] = phi;
  }
  __syncthreads();   // red ready; all loop LDS reads done (U reusable)

  // exchange non-kept ctx halves via U: writer slot [wh]
  {
    const int nfs = wh ? 0 : 2;
#pragma unroll
    for (int k2 = 0; k2 < 2; ++k2)
#pragma unroll
      for (int reg = 0; reg < 4; ++reg)
        ctxredf[((wh * 64) + wq + g * 4 + reg) * 36 + k2 * 16 + cl] = ctx[nfs + k2][reg];
  }
  if (tid < 64) {
    lsum_s[tid]    = red[0][0][tid] + red[1][0][tid];
    T[tid][0]      = (bf16)(red[0][1][tid] + red[1][1][tid]);
    T[tid][2 * R_] = (bf16)(red[0][2][tid] + red[1][2][tid]);
  }
  for (int t = tid; t < 64 * 32; t += 512) {
    const int c = t & 31;
    if (c) T[t >> 5][256 + c] = (bf16)0.f;
  }
  if (q0 < R_ || q0 > S_ - R_ - 64) {
    for (int t = tid; t < 64 * 256; t += 512) {
      const int r = t >> 8, c = t & 255;
      if (c >= 1) {
        const int j = q0 + r + c - R_;
        if (j < 0 || j >= S_) T[r][c] = (bf16)0.f;
      }
    }
  }
  __syncthreads();

  // complete kept halves with peer's partials
  const int nfa = wh ? 2 : 0;
  f32x4 cx0 = ctx[nfa], cx1 = ctx[nfa + 1];
#pragma unroll
  for (int reg = 0; reg < 4; ++reg) {
    cx0[reg] += ctxredf[(((wh ^ 1) * 64) + wq + g * 4 + reg) * 36 + cl];
    cx1[reg] += ctxredf[(((wh ^ 1) * 64) + wq + g * 4 + reg) * 36 + 16 + cl];
  }

  // rel-value GEMM: ctx += T(relp)[64][288] @ rvE
#pragma unroll
  for (int ks = 0; ks < 9; ++ks) {
    const bf16x8 pa = *(const bf16x8*)&T[lq][ks * 32 + kg8];
    const bf16x8 v0 = *(const bf16x8*)(rvTb + (size_t)(wh * 32 + cl) * 288 + ks * 32 + kg8);
    const bf16x8 v1 = *(const bf16x8*)(rvTb + (size_t)(wh * 32 + 16 + cl) * 288 + ks * 32 + kg8);
    __builtin_amdgcn_s_setprio(1);
    cx0 = mfma16(pa, v0, cx0);
    cx1 = mfma16(pa, v1, cx1);
    __builtin_amdgcn_s_setprio(0);
  }

#pragma unroll
  for (int reg = 0; reg < 4; ++reg) {
    const int qrow = wq + g * 4 + reg;
    const float invl = 1.f / lsum_s[qrow];
    float* op = out + (size_t)(b * S_ + q0 + qrow) * HID_ + h * 64 + wh * 32;
    op[cl]      = cx0[reg] * invl;
    op[16 + cl] = cx1[reg] * invl;
  }
}

extern "C" void kernel_launch(void* const* d_in, const int* in_sizes, int n_in,
                              void* d_out, int out_size, void* d_ws, size_t ws_size,
                              hipStream_t stream)
{
  (void)in_sizes; (void)n_in; (void)out_size; (void)ws_size;
  const float* hidden  = (const float*)d_in[0];
  const float* st_mask = (const float*)d_in[1];
  const float* Wq = (const float*)d_in[2];
  const float* bq = (const float*)d_in[3];
  const float* Wk = (const float*)d_in[4];
  const float* bk = (const float*)d_in[5];
  const float* Wv = (const float*)d_in[6];
  const float* bv = (const float*)d_in[7];
  const float* rkE = (const float*)d_in[8];
  const float* rvE = (const float*)d_in[9];
  float* out = (float*)d_out;

  const size_t per = (size_t)B_ * H_ * S_ * D_;   // 4,194,304 elements
  char* wsb = (char*)d_ws;
  float* msk2 = (float*)wsb;                               // 16384 B
  bf16*  rkEb = (bf16*)(wsb + 16384);                      // 34816 B
  bf16*  rvTb = (bf16*)(wsb + 16384 + 34816);              // 36864 B
  char*  base1 = wsb + 16384 + 34816 + 36864;
  bf16* Qh = (bf16*)base1;
  bf16* Ql = Qh + per;
  bf16* Kb = Ql + per;
  bf16* Vt = Kb + per;
  bf16* Ahg = Vt + per;
  bf16* Alg = Ahg + per;
  bf16* Wbg = Alg + per;

  prep_kernel<<<dim3(1024), 256, 0, stream>>>(
      st_mask, rkE, rvE, hidden, Wq, Wk, Wv, msk2, rkEb, rvTb, Ahg, Alg, Wbg);
  qkv_mfma_kernel<<<dim3(512), 256, 0, stream>>>(
      Ahg, Alg, Wbg, bq, bk, bv, Qh, Ql, Kb, Vt);
  attn_kernel<<<dim3(1024), 512, 0, stream>>>(
      Qh, Ql, Kb, Vt, msk2, rkEb, rvTb, out);
}

// Round 16
// 160.049 us; speedup vs baseline: 1.4263x; 1.0414x over previous
//
#include <hip/hip_runtime.h>
#include <math.h>

typedef __bf16 bf16;
typedef __bf16 bf16x8 __attribute__((ext_vector_type(8)));
typedef __bf16 bf16x4 __attribute__((ext_vector_type(4)));
typedef float  f32x4  __attribute__((ext_vector_type(4)));

namespace {
constexpr int B_ = 2, S_ = 2048, HID_ = 1024, H_ = 16, D_ = 64, R_ = 128, NREL_ = 257;
constexpr float LOG2E_ = 1.44269504f;
constexpr float QSC_ = 0.125f * LOG2E_;   // 1/sqrt(D) and log2(e), folded into Q
}

static __device__ __forceinline__ f32x4 mfma16(bf16x8 a, bf16x8 b, f32x4 c) {
  return __builtin_amdgcn_mfma_f32_16x16x32_bf16(a, b, c, 0, 0, 0);
}
static __device__ __forceinline__ void split2(float f, bf16 &hi, bf16 &lo) {
  hi = (bf16)f; lo = (bf16)(f - (float)hi);
}
static __device__ __forceinline__ float fexp2(float x) {
  return __builtin_amdgcn_exp2f(x);
}
// async global->LDS, 16B per lane. dst must be wave-uniform base (+lane*16 by HW).
static __device__ __forceinline__ void gload16(const bf16* g, bf16* l) {
  __builtin_amdgcn_global_load_lds(
      (const __attribute__((address_space(1))) void*)g,
      (__attribute__((address_space(3))) void*)l, 16, 0, 0);
}

// ---------------- prep: mask, rkE*8, rvE^T, hidden split (Ah/Al), W -> bf16
__global__ __launch_bounds__(256) void prep_kernel(
    const float* __restrict__ st_mask, const float* __restrict__ rkE,
    const float* __restrict__ rvE, const float* __restrict__ hidden,
    const float* __restrict__ Wq, const float* __restrict__ Wk,
    const float* __restrict__ Wv,
    float* __restrict__ msk2, bf16* __restrict__ rkEb, bf16* __restrict__ rvTb,
    bf16* __restrict__ Ahg, bf16* __restrict__ Alg, bf16* __restrict__ Wbg)
{
  const int t0 = blockIdx.x * 256 + threadIdx.x;
  const int NT = gridDim.x * 256;
  for (int t = t0; t < B_ * S_; t += NT)
    msk2[t] = (1.f - st_mask[t]) * -10000.f * LOG2E_;
  for (int t = t0; t < 272 * 64; t += NT) {
    const int bk = t >> 6, d = t & 63;
    rkEb[t] = (bk < NREL_) ? (bf16)(rkE[bk * D_ + d] * 8.0f) : (bf16)0.f;
  }
  for (int t = t0; t < 64 * 288; t += NT) {
    const int d = t / 288, c = t - d * 288;
    rvTb[t] = (c < NREL_) ? (bf16)rvE[c * D_ + d] : (bf16)0.f;
  }
  for (int t = t0; t < (B_ * S_ * HID_) / 4; t += NT) {
    const float4 a = ((const float4*)hidden)[t];
    const float av[4] = {a.x, a.y, a.z, a.w};
    bf16x4 h, o;
#pragma unroll
    for (int i = 0; i < 4; ++i) {
      bf16 th, tl;
      split2(av[i], th, tl);
      h[i] = th; o[i] = tl;
    }
    *(bf16x4*)&Ahg[t * 4] = h;
    *(bf16x4*)&Alg[t * 4] = o;
  }
  for (int t = t0; t < 3 * (HID_ * HID_) / 4; t += NT) {
    const int s = t >> 18, i = t & 262143;
    const float4 wv4 = ((const float4*)(s == 0 ? Wq : s == 1 ? Wk : Wv))[i];
    bf16x4 h;
    h[0] = (bf16)wv4.x; h[1] = (bf16)wv4.y; h[2] = (bf16)wv4.z; h[3] = (bf16)wv4.w;
    *(bf16x4*)&Wbg[s * 1048576 + i * 4] = h;
  }
}

// ---------------- qkv GEMM (passed r10-r15). V written TILED [B,H, S/64, D, 64]
// with sigma-permuted columns (PV A-operand needs no shuffle).
__global__ __launch_bounds__(256, 2) void qkv_mfma_kernel(
    const bf16* __restrict__ Ahg, const bf16* __restrict__ Alg,
    const bf16* __restrict__ Wbg,
    const float* __restrict__ bq, const float* __restrict__ bk,
    const float* __restrict__ bv,
    bf16* __restrict__ Qh, bf16* __restrict__ Ql,
    bf16* __restrict__ Kb, bf16* __restrict__ Vt)
{
  const int swz = ((int)blockIdx.x & 7) * 64 + ((int)blockIdx.x >> 3);
  const int m0 = (swz >> 4) * 128;
  const int n0 = (swz & 15) * 64;
  const int tid = threadIdx.x;
  const int l = tid & 63, w = tid >> 6;
  const int cl = l & 15, g = l >> 4;

  __shared__ __align__(16) bf16 AhS[2][4096];
  __shared__ __align__(16) bf16 AlS[2][4096];
  __shared__ __align__(16) bf16 WS[2][3][2048];

  const int r0 = tid >> 2;
  const int csw = (((tid & 3) ^ (r0 & 3)) << 3);
  const size_t aoff0 = (size_t)(m0 + r0) * HID_ + csw;
  const size_t aoff1 = (size_t)(m0 + 64 + r0) * HID_ + csw;
  const size_t woff  = (size_t)(n0 + r0) * HID_ + csw;
  const int wb = w * 512;

  const int rA0 = w * 16 + cl;
  const int eA0 = rA0 * 32 + 8 * (g ^ (rA0 & 3));
  const int eA1 = eA0 + 2048;
  const int eW  = cl * 32 + 8 * (g ^ (cl & 3));

  f32x4 acc[2][3][4];
#pragma unroll
  for (int hf = 0; hf < 2; ++hf)
#pragma unroll
    for (int s = 0; s < 3; ++s)
#pragma unroll
      for (int nf = 0; nf < 4; ++nf)
#pragma unroll
        for (int i = 0; i < 4; ++i) acc[hf][s][nf][i] = 0.f;

  gload16(Ahg + aoff0, &AhS[0][wb]);
  gload16(Ahg + aoff1, &AhS[0][2048 + wb]);
  gload16(Alg + aoff0, &AlS[0][wb]);
  gload16(Alg + aoff1, &AlS[0][2048 + wb]);
  gload16(Wbg + woff,           &WS[0][0][wb]);
  gload16(Wbg + 1048576 + woff, &WS[0][1][wb]);
  gload16(Wbg + 2097152 + woff, &WS[0][2][wb]);
  __syncthreads();

  int cur = 0;
  for (int kt = 0; kt < HID_ / 32; ++kt) {
    if (kt + 1 < HID_ / 32) {
      const size_t ko = (size_t)(kt + 1) * 32;
      bf16* ah = &AhS[cur ^ 1][0]; bf16* al = &AlS[cur ^ 1][0];
      gload16(Ahg + aoff0 + ko, ah + wb);
      gload16(Ahg + aoff1 + ko, ah + 2048 + wb);
      gload16(Alg + aoff0 + ko, al + wb);
      gload16(Alg + aoff1 + ko, al + 2048 + wb);
      gload16(Wbg + woff + ko,           &WS[cur ^ 1][0][wb]);
      gload16(Wbg + 1048576 + woff + ko, &WS[cur ^ 1][1][wb]);
      gload16(Wbg + 2097152 + woff + ko, &WS[cur ^ 1][2][wb]);
    }

    const bf16x8 fah0 = *(const bf16x8*)&AhS[cur][eA0];
    const bf16x8 fah1 = *(const bf16x8*)&AhS[cur][eA1];
    const bf16x8 fal0 = *(const bf16x8*)&AlS[cur][eA0];
    const bf16x8 fal1 = *(const bf16x8*)&AlS[cur][eA1];
#pragma unroll
    for (int s = 0; s < 3; ++s)
#pragma unroll
      for (int nf = 0; nf < 4; ++nf) {
        const bf16x8 fb = *(const bf16x8*)&WS[cur][s][nf * 512 + eW];
        acc[0][s][nf] = mfma16(fah0, fb, acc[0][s][nf]);
        acc[0][s][nf] = mfma16(fal0, fb, acc[0][s][nf]);
        acc[1][s][nf] = mfma16(fah1, fb, acc[1][s][nf]);
        acc[1][s][nf] = mfma16(fal1, fb, acc[1][s][nf]);
      }
    __syncthreads();
    cur ^= 1;
  }

  const float* bs_[3] = {bq, bk, bv};
#pragma unroll
  for (int s = 0; s < 3; ++s)
#pragma unroll
    for (int nf = 0; nf < 4; ++nf) {
      const int n = n0 + nf * 16 + cl;
      const float bias = bs_[s][n];
      const int hd = n >> 6, d = n & 63;
#pragma unroll
      for (int hf = 0; hf < 2; ++hf)
#pragma unroll
        for (int reg = 0; reg < 4; ++reg) {
          const int m = m0 + hf * 64 + w * 16 + g * 4 + reg;
          const int b = m >> 11, sq = m & (S_ - 1);
          const float val = acc[hf][s][nf][reg] + bias;
          if (s == 0) {
            bf16 h, o; split2(val * QSC_, h, o);
            const size_t idx = ((size_t)(b * H_ + hd) * S_ + sq) * D_ + d;
            Qh[idx] = h; Ql[idx] = o;
          } else if (s == 1) {
            Kb[((size_t)(b * H_ + hd) * S_ + sq) * D_ + d] = (bf16)val;
          } else {
            const int jo = sq & 63;
            const int mc = (jo & 32) | (((jo >> 3) & 1) << 4) | (((jo >> 2) & 1) << 3)
                         | (((jo >> 4) & 1) << 2) | (jo & 3);
            Vt[(((size_t)(b * H_ + hd) * (S_ / 64) + (sq >> 6)) * D_ + d) * 64 + mc]
                = (bf16)val;
          }
        }
    }
}

// ---------------- attention v16: counted vmcnt + raw barrier. K triple-buffered
// (depth-2 prefetch), V double (depth-1), mask staged in LDS bf16, T[64][272]
// with bucket-256 handled as a scalar phi-tail in the epilogue.
__global__ __launch_bounds__(512, 4) void attn_kernel(
    const bf16* __restrict__ Qh, const bf16* __restrict__ Ql,
    const bf16* __restrict__ Kb, const bf16* __restrict__ Vt,
    const float* __restrict__ msk2, const bf16* __restrict__ rkEb,
    const bf16* __restrict__ rvTb, float* __restrict__ out)
{
  constexpr int NT = S_ / 64;    // 32 tiles
  const int swz = ((int)blockIdx.x & 7) * 128 + ((int)blockIdx.x >> 3);
  const int qt = swz & 31, h = (swz >> 5) & 15, b = swz >> 9;
  const int q0 = qt * 64;
  const int tid = threadIdx.x;
  const int l = tid & 63, w = tid >> 6;
  const int wq = (w & 3) * 16;
  const int wh = w >> 2;
  const int cl = l & 15, g = l >> 4, kg8 = g * 8;
  const int lq = wq + cl;

  // K triple (24K) + V double (16K); ctxred [2][64][36] f32 aliases this after loop
  __shared__ __align__(16) unsigned char U[40960];
  __shared__ __align__(16) bf16 T[64][272];     // rs then relp (cols 0..255 + 256=rs_hi)
  __shared__ __align__(16) bf16 msk_l[S_];      // bf16 mask*log2e, whole batch-row
  __shared__ float red[2][3][64];

  bf16* kA = (bf16*)&U[0];
  bf16* kB = (bf16*)&U[8192];
  bf16* kC = (bf16*)&U[16384];
  bf16* vA = (bf16*)&U[24576];
  bf16* vB = (bf16*)&U[32768];
  float* ctxredf = (float*)&U[0];               // after loop

  const size_t bh = (size_t)(b * H_ + h) * S_;
  const bf16* Kbase = Kb + bh * D_;             // [S][64]
  const bf16* Vbase = Vt + bh * D_;             // tiled [S/64][64][64], sigma cols
  const float* mbase = msk2 + b * S_;

  const int tKr = tid >> 3;
  const int koff = tKr * 64 + (((tid & 7) ^ (tKr & 7)) << 3);

  // prologue staging: K(0), K(1), V(0)
  gload16(Kbase + koff,        kA + w * 512);
  gload16(Kbase + 4096 + koff, kB + w * 512);
  gload16(Vbase + koff,        vA + w * 512);

  // mask -> LDS bf16
  {
    const float4 m4 = *(const float4*)(mbase + tid * 4);
    bf16x4 mb;
    mb[0] = (bf16)m4.x; mb[1] = (bf16)m4.y; mb[2] = (bf16)m4.z; mb[3] = (bf16)m4.w;
    *(bf16x4*)&msk_l[tid * 4] = mb;
  }

  bf16x8 qh0, qh1, ql0, ql1;
  {
    const size_t base = (bh + q0 + lq) * D_ + kg8;
    qh0 = *(const bf16x8*)(Qh + base);
    qh1 = *(const bf16x8*)(Qh + base + 32);
    ql0 = *(const bf16x8*)(Ql + base);
    ql1 = *(const bf16x8*)(Ql + base + 32);
  }

  // rel key scores into T
  {
    const int nt0 = wh ? 9 : 0, ntE = wh ? 17 : 9;
    for (int nt = nt0; nt < ntE; ++nt) {
      f32x4 r; r[0] = r[1] = r[2] = r[3] = 0.f;
      const bf16x8 a0 = *(const bf16x8*)(rkEb + (size_t)(nt * 16 + cl) * 64 + kg8);
      const bf16x8 a1 = *(const bf16x8*)(rkEb + (size_t)(nt * 16 + cl) * 64 + 32 + kg8);
      r = mfma16(a0, qh0, r); r = mfma16(a0, ql0, r);
      r = mfma16(a1, qh1, r); r = mfma16(a1, ql1, r);
      bf16x4 pk;
#pragma unroll
      for (int reg = 0; reg < 4; ++reg) pk[reg] = (bf16)r[reg];
      *(bf16x4*)&T[lq][nt * 16 + g * 4] = pk;
    }
  }
  __syncthreads();   // T + mask ready; prologue stages drained

  const float rs_lo = (float)T[lq][0];
  const float rs_hi = (float)T[lq][2 * R_];
  const int qg = q0 + lq;

  f32x4 ctx[4];
#pragma unroll
  for (int nf = 0; nf < 4; ++nf) { ctx[nf][0]=0.f; ctx[nf][1]=0.f; ctx[nf][2]=0.f; ctx[nf][3]=0.f; }
  float lsum = 0.f, plo = 0.f, phi = 0.f;

  const int r00 = wh * 32 + cl, r10 = wh * 32 + 16 + cl;
  const int e00 = r00 * 64 + 8 * (g ^ (r00 & 7)), e01 = r00 * 64 + 8 * ((4 + g) ^ (r00 & 7));
  const int e10 = r10 * 64 + 8 * (g ^ (r10 & 7)), e11 = r10 * 64 + 8 * ((4 + g) ^ (r10 & 7));
  int fv0, fv1, fv2, fv3;
  {
    const int rd0 = cl, rd1 = 16 + cl, rd2 = 32 + cl, rd3 = 48 + cl;
    fv0 = rd0 * 64 + 8 * ((4 * wh + g) ^ (rd0 & 7));
    fv1 = rd1 * 64 + 8 * ((4 * wh + g) ^ (rd1 & 7));
    fv2 = rd2 * 64 + 8 * ((4 * wh + g) ^ (rd2 & 7));
    fv3 = rd3 * 64 + 8 * ((4 * wh + g) ^ (rd3 & 7));
  }

  bf16* kR = kA; bf16* kM = kB; bf16* kW = kC;   // read / in-flight / stage-target
  bf16* vR = vA; bf16* vW = vB;

  for (int kt = 0; kt < NT; ++kt) {
    // issue: K depth-2, V depth-1
    if (kt + 2 < NT) gload16(Kbase + (size_t)(kt + 2) * 4096 + koff, kW + w * 512);
    if (kt + 1 < NT) gload16(Vbase + (size_t)(kt + 1) * 4096 + koff, vW + w * 512);

    const bf16x8 a00 = *(const bf16x8*)&kR[e00];
    const bf16x8 a01 = *(const bf16x8*)&kR[e01];
    const bf16x8 a10 = *(const bf16x8*)&kR[e10];
    const bf16x8 a11 = *(const bf16x8*)&kR[e11];

    f32x4 s0, s1;
    s0[0]=s0[1]=s0[2]=s0[3]=0.f; s1[0]=s1[1]=s1[2]=s1[3]=0.f;
    __builtin_amdgcn_s_setprio(1);
    s0 = mfma16(a00, qh0, s0); s0 = mfma16(a00, ql0, s0);
    s0 = mfma16(a01, qh1, s0); s0 = mfma16(a01, ql1, s0);
    s1 = mfma16(a10, qh0, s1); s1 = mfma16(a10, ql0, s1);
    s1 = mfma16(a11, qh1, s1); s1 = mfma16(a11, ql1, s1);
    __builtin_amdgcn_s_setprio(0);

    const int j0 = kt * 64 + wh * 32;
    const bf16x4 mb0 = *(const bf16x4*)&msk_l[j0 + g * 4];
    const bf16x4 mb1 = *(const bf16x4*)&msk_l[j0 + 16 + g * 4];
    const int dlt = kt * 64 - q0;
    const int mode = (dlt <= -192) ? 0 : (dlt >= 192 ? 1 : 2);

    bf16x4 pk0, pk1;
#pragma unroll
    for (int nf = 0; nf < 2; ++nf) {
      const f32x4 sa = nf ? s1 : s0;
      const bf16x4 mkv = nf ? mb1 : mb0;
      float mks[4];
#pragma unroll
      for (int i = 0; i < 4; ++i) mks[i] = (float)mkv[i];
      float p[4];
      if (mode == 0) {
#pragma unroll
        for (int reg = 0; reg < 4; ++reg) p[reg] = fexp2(sa[reg] + rs_lo + mks[reg]);
        plo += (p[0] + p[1]) + (p[2] + p[3]);
      } else if (mode == 1) {
#pragma unroll
        for (int reg = 0; reg < 4; ++reg) p[reg] = fexp2(sa[reg] + rs_hi + mks[reg]);
        phi += (p[0] + p[1]) + (p[2] + p[3]);
      } else {
        const int jb = j0 + nf * 16 + g * 4;
#pragma unroll
        for (int reg = 0; reg < 4; ++reg) {
          const int bkv = jb + reg - qg + R_;
          const int bkc = bkv < 0 ? 0 : (bkv > 2 * R_ ? 2 * R_ : bkv);
          const float pv = fexp2(sa[reg] + (float)T[lq][bkc] + mks[reg]);
          p[reg] = pv;
          if (bkv <= 0)           plo += pv;
          else if (bkv >= 2 * R_) phi += pv;
          else                    T[lq][bkv] = (bf16)pv;   // unique owner cell
        }
      }
      lsum += (p[0] + p[1]) + (p[2] + p[3]);
      bf16x4 pk;
#pragma unroll
      for (int reg = 0; reg < 4; ++reg) pk[reg] = (bf16)p[reg];
      if (nf == 0) pk0 = pk; else pk1 = pk;
    }

    // drain K(kt+1) & V(kt): both issued >= 1 full compute-phase ago
    if (kt < NT - 2)      asm volatile("s_waitcnt vmcnt(2)" ::: "memory");
    else if (kt == NT - 2) asm volatile("s_waitcnt vmcnt(1)" ::: "memory");
    else                  asm volatile("s_waitcnt vmcnt(0)" ::: "memory");
    __builtin_amdgcn_sched_barrier(0);

    // PV: A-operand = packed p's (sigma ordering)
    const bf16x8 pa = __builtin_shufflevector(pk0, pk1, 0, 1, 2, 3, 4, 5, 6, 7);
    __builtin_amdgcn_s_setprio(1);
    ctx[0] = mfma16(pa, *(const bf16x8*)&vR[fv0], ctx[0]);
    ctx[1] = mfma16(pa, *(const bf16x8*)&vR[fv1], ctx[1]);
    ctx[2] = mfma16(pa, *(const bf16x8*)&vR[fv2], ctx[2]);
    ctx[3] = mfma16(pa, *(const bf16x8*)&vR[fv3], ctx[3]);
    __builtin_amdgcn_s_setprio(0);

    // drain V(kt+1) before the barrier; keep K(kt+2) in flight
    if (kt < NT - 2) asm volatile("s_waitcnt vmcnt(1)" ::: "memory");
    else             asm volatile("s_waitcnt vmcnt(0)" ::: "memory");
    __builtin_amdgcn_sched_barrier(0);
    __builtin_amdgcn_s_barrier();          // raw: no full drain
    __builtin_amdgcn_sched_barrier(0);

    // rotate buffers
    bf16* t0 = kR; kR = kM; kM = kW; kW = t0;
    bf16* t1 = vR; vR = vW; vW = t1;
  }

  // lane-group reductions (q fixed per lane)
  lsum += __shfl_xor(lsum, 16); lsum += __shfl_xor(lsum, 32);
  plo  += __shfl_xor(plo, 16);  plo  += __shfl_xor(plo, 32);
  phi  += __shfl_xor(phi, 16);  phi  += __shfl_xor(phi, 32);
  if (l < 16) {
    red[wh][0][wq + l] = lsum;
    red[wh][1][wq + l] = plo;
    red[wh][2][wq + l] = phi;
  }
  __syncthreads();   // red ready; all loop LDS reads done (U reusable)

  // exchange non-kept ctx halves via U
  {
    const int nfs = wh ? 0 : 2;
#pragma unroll
    for (int k2 = 0; k2 < 2; ++k2)
#pragma unroll
      for (int reg = 0; reg < 4; ++reg)
        ctxredf[((wh * 64) + wq + g * 4 + reg) * 36 + k2 * 16 + cl] = ctx[nfs + k2][reg];
  }
  if (tid < 64) {
    red[0][0][tid] += red[1][0][tid];                     // lsum
    T[tid][0] = (bf16)(red[0][1][tid] + red[1][1][tid]);  // plo -> bucket 0
    red[0][2][tid] += red[1][2][tid];                     // phi (f32, scalar tail)
  }
  // zero interior cells whose j is out of range (edge q-tiles only)
  if (q0 < R_ || q0 > S_ - R_ - 64) {
    for (int t = tid; t < 64 * 256; t += 512) {
      const int r = t >> 8, c = t & 255;
      if (c >= 1) {
        const int j = q0 + r + c - R_;
        if (j < 0 || j >= S_) T[r][c] = (bf16)0.f;
      }
    }
  }
  __syncthreads();

  // complete kept halves with peer's partials
  const int nfa = wh ? 2 : 0;
  f32x4 cx0 = ctx[nfa], cx1 = ctx[nfa + 1];
#pragma unroll
  for (int reg = 0; reg < 4; ++reg) {
    cx0[reg] += ctxredf[(((wh ^ 1) * 64) + wq + g * 4 + reg) * 36 + cl];
    cx1[reg] += ctxredf[(((wh ^ 1) * 64) + wq + g * 4 + reg) * 36 + 16 + cl];
  }

  // rel-value GEMM: buckets 0..255 (bucket 256 via scalar phi-tail)
#pragma unroll
  for (int ks = 0; ks < 8; ++ks) {
    const bf16x8 pa = *(const bf16x8*)&T[lq][ks * 32 + kg8];
    const bf16x8 v0 = *(const bf16x8*)(rvTb + (size_t)(wh * 32 + cl) * 288 + ks * 32 + kg8);
    const bf16x8 v1 = *(const bf16x8*)(rvTb + (size_t)(wh * 32 + 16 + cl) * 288 + ks * 32 + kg8);
    __builtin_amdgcn_s_setprio(1);
    cx0 = mfma16(pa, v0, cx0);
    cx1 = mfma16(pa, v1, cx1);
    __builtin_amdgcn_s_setprio(0);
  }
  const float rv256a = (float)rvTb[(size_t)(wh * 32 + cl) * 288 + 256];
  const float rv256b = (float)rvTb[(size_t)(wh * 32 + 16 + cl) * 288 + 256];

#pragma unroll
  for (int reg = 0; reg < 4; ++reg) {
    const int qrow = wq + g * 4 + reg;
    const float invl = 1.f / red[0][0][qrow];
    const float phq  = red[0][2][qrow];
    float* op = out + (size_t)(b * S_ + q0 + qrow) * HID_ + h * 64 + wh * 32;
    op[cl]      = (cx0[reg] + phq * rv256a) * invl;
    op[16 + cl] = (cx1[reg] + phq * rv256b) * invl;
  }
}

extern "C" void kernel_launch(void* const* d_in, const int* in_sizes, int n_in,
                              void* d_out, int out_size, void* d_ws, size_t ws_size,
                              hipStream_t stream)
{
  (void)in_sizes; (void)n_in; (void)out_size; (void)ws_size;
  const float* hidden  = (const float*)d_in[0];
  const float* st_mask = (const float*)d_in[1];
  const float* Wq = (const float*)d_in[2];
  const float* bq = (const float*)d_in[3];
  const float* Wk = (const float*)d_in[4];
  const float* bk = (const float*)d_in[5];
  const float* Wv = (const float*)d_in[6];
  const float* bv = (const float*)d_in[7];
  const float* rkE = (const float*)d_in[8];
  const float* rvE = (const float*)d_in[9];
  float* out = (float*)d_out;

  const size_t per = (size_t)B_ * H_ * S_ * D_;   // 4,194,304 elements
  char* wsb = (char*)d_ws;
  float* msk2 = (float*)wsb;                               // 16384 B
  bf16*  rkEb = (bf16*)(wsb + 16384);                      // 34816 B
  bf16*  rvTb = (bf16*)(wsb + 16384 + 34816);              // 36864 B
  char*  base1 = wsb + 16384 + 34816 + 36864;
  bf16* Qh = (bf16*)base1;
  bf16* Ql = Qh + per;
  bf16* Kb = Ql + per;
  bf16* Vt = Kb + per;
  bf16* Ahg = Vt + per;
  bf16* Alg = Ahg + per;
  bf16* Wbg = Alg + per;

  prep_kernel<<<dim3(1024), 256, 0, stream>>>(
      st_mask, rkE, rvE, hidden, Wq, Wk, Wv, msk2, rkEb, rvTb, Ahg, Alg, Wbg);
  qkv_mfma_kernel<<<dim3(512), 256, 0, stream>>>(
      Ahg, Alg, Wbg, bq, bk, bv, Qh, Ql, Kb, Vt);
  attn_kernel<<<dim3(1024), 512, 0, stream>>>(
      Qh, Ql, Kb, Vt, msk2, rkEb, rvTb, out);
}